// Round 1
// baseline (2225.204 us; speedup 1.0000x reference)
//
#include <hip/hip_runtime.h>
#include <hip/hip_bf16.h>

// GCN forward: 2x GCNConv(relu) -> global_mean_pool -> MLP head.
// N=100000, E=1200000, IN_CH=22, HID=64, NUM_CLASSES=3, G=256 (derived from sizes).

#define HIDC 64

__global__ void k_init_deg(float* deg, int n) {
    int i = blockIdx.x * blockDim.x + threadIdx.x;
    if (i < n) deg[i] = 1.0f;   // self-loop weight
}

__global__ void k_deg_accum(const int* __restrict__ col, const float* __restrict__ w,
                            float* deg, int E) {
    int e = blockIdx.x * blockDim.x + threadIdx.x;
    if (e < E) atomicAdd(&deg[col[e]], w[e]);
}

__global__ void k_deg_to_dinv(float* deg, int n) {
    int i = blockIdx.x * blockDim.x + threadIdx.x;
    if (i < n) deg[i] = rsqrtf(deg[i]);   // deg >= 1 always (self-loop)
}

__global__ void k_compute_norm(const int* __restrict__ row, const int* __restrict__ col,
                               const float* __restrict__ w, const float* __restrict__ dinv,
                               float* __restrict__ norm, int E) {
    int e = blockIdx.x * blockDim.x + threadIdx.x;
    if (e < E) norm[e] = dinv[row[e]] * w[e] * dinv[col[e]];
}

// h[n][64] = x[n][K] @ W[K][64]   (bias applied later, after aggregation)
template <int K>
__global__ void k_gemm_node(const float* __restrict__ x, const float* __restrict__ W,
                            float* __restrict__ h, int n) {
    __shared__ float sW[K * HIDC];
    for (int i = threadIdx.x; i < K * HIDC; i += blockDim.x) sW[i] = W[i];
    __syncthreads();
    int t = blockIdx.x * blockDim.x + threadIdx.x;
    int node = t >> 6, c = t & 63;
    if (node >= n) return;
    const float* xr = x + (size_t)node * K;
    float acc = 0.f;
#pragma unroll
    for (int k = 0; k < K; ++k) acc = fmaf(xr[k], sW[k * HIDC + c], acc);
    h[(size_t)node * HIDC + c] = acc;
}

// out[i][c] = dinv[i]^2 * h[i][c]   (the self-loop contribution)
__global__ void k_agg_init(const float* __restrict__ h, const float* __restrict__ dinv,
                           float* __restrict__ out, int n) {
    int t = blockIdx.x * blockDim.x + threadIdx.x;
    int node = t >> 6, c = t & 63;
    if (node >= n) return;
    float d = dinv[node];
    out[(size_t)node * HIDC + c] = d * d * h[(size_t)node * HIDC + c];
}

// 16 threads per edge; each thread does a float4 gather + 4 scalar atomics.
__global__ void k_agg_edges(const int* __restrict__ row, const int* __restrict__ col,
                            const float* __restrict__ norm, const float* __restrict__ h,
                            float* __restrict__ out, int E) {
    int t = blockIdx.x * blockDim.x + threadIdx.x;
    int e = t >> 4;
    if (e >= E) return;
    int q = (t & 15) * 4;
    int r = row[e], c = col[e];
    float nm = norm[e];
    const float4 hv = *reinterpret_cast<const float4*>(h + (size_t)r * HIDC + q);
    float* op = out + (size_t)c * HIDC + q;
    atomicAdd(op + 0, nm * hv.x);
    atomicAdd(op + 1, nm * hv.y);
    atomicAdd(op + 2, nm * hv.z);
    atomicAdd(op + 3, nm * hv.w);
}

__global__ void k_bias_relu(float* __restrict__ out, const float* __restrict__ b, int n) {
    int t = blockIdx.x * blockDim.x + threadIdx.x;
    int node = t >> 6, c = t & 63;
    if (node >= n) return;
    size_t idx = (size_t)node * HIDC + c;
    out[idx] = fmaxf(out[idx] + b[c], 0.f);
}

__global__ void k_zero(float* p, int n) {
    int i = blockIdx.x * blockDim.x + threadIdx.x;
    if (i < n) p[i] = 0.f;
}

// batch is sorted: segmented accumulate, flush (atomic) only on graph change.
// Block handles 256 consecutive nodes; thread = (sub-node-stride 4, channel).
__global__ void k_pool(const float* __restrict__ h, const int* __restrict__ batch,
                       float* __restrict__ pooled, int n) {
    int c = threadIdx.x & 63, sub = threadIdx.x >> 6;
    int n0 = blockIdx.x * 256;
    int nend = min(n0 + 256, n);
    float acc = 0.f;
    int curb = -1;
    for (int i = n0 + sub; i < nend; i += 4) {
        int b = batch[i];
        if (b != curb) {
            if (curb >= 0) atomicAdd(&pooled[curb * HIDC + c], acc);
            acc = 0.f;
            curb = b;
        }
        acc += h[(size_t)i * HIDC + c];
    }
    if (curb >= 0) atomicAdd(&pooled[curb * HIDC + c], acc);
}

__global__ void k_count(const int* __restrict__ batch, float* __restrict__ cnt, int n) {
    int t = blockIdx.x * blockDim.x + threadIdx.x;
    int i0 = t * 64;
    if (i0 >= n) return;
    int end = min(i0 + 64, n);
    int curb = batch[i0];
    float acc = 0.f;
    for (int i = i0; i < end; ++i) {
        int b = batch[i];
        if (b != curb) {
            atomicAdd(&cnt[curb], acc);
            acc = 0.f;
            curb = b;
        }
        acc += 1.f;
    }
    atomicAdd(&cnt[curb], acc);
}

// One 64-thread block per graph: mean, fc1+relu, fc2.
__global__ void k_head(const float* __restrict__ pooled, const float* __restrict__ cnt,
                       const float* __restrict__ fw1, const float* __restrict__ fb1,
                       const float* __restrict__ fw2, const float* __restrict__ fb2,
                       float* __restrict__ out, int nclass) {
    int g = blockIdx.x;
    int j = threadIdx.x;   // 0..63
    __shared__ float p[HIDC], hid[HIDC];
    float c = fmaxf(cnt[g], 1.0f);
    p[j] = pooled[g * HIDC + j] / c;
    __syncthreads();
    float acc = fb1[j];
#pragma unroll 8
    for (int k = 0; k < HIDC; ++k) acc = fmaf(p[k], fw1[k * HIDC + j], acc);
    hid[j] = fmaxf(acc, 0.f);
    __syncthreads();
    if (j < nclass) {
        float o = fb2[j];
#pragma unroll 8
        for (int k = 0; k < HIDC; ++k) o = fmaf(hid[k], fw2[k * nclass + j], o);
        out[g * nclass + j] = o;
    }
}

extern "C" void kernel_launch(void* const* d_in, const int* in_sizes, int n_in,
                              void* d_out, int out_size, void* d_ws, size_t ws_size,
                              hipStream_t stream) {
    const float* x    = (const float*)d_in[0];
    const int* eidx   = (const int*)d_in[1];
    const float* ew   = (const float*)d_in[2];
    const int* batch  = (const int*)d_in[3];
    const float* W1   = (const float*)d_in[4];
    const float* b1   = (const float*)d_in[5];
    const float* W2   = (const float*)d_in[6];
    const float* b2   = (const float*)d_in[7];
    const float* fw1  = (const float*)d_in[8];
    const float* fb1  = (const float*)d_in[9];
    const float* fw2  = (const float*)d_in[10];
    const float* fb2  = (const float*)d_in[11];
    float* out = (float*)d_out;

    const int N = in_sizes[3];                // batch vector length
    const int E = in_sizes[1] / 2;            // edge_index is (2, E)
    const int NCLASS = in_sizes[11];          // fb2 length
    const int G = out_size / NCLASS;

    const int* row = eidx;
    const int* col = eidx + E;

    // workspace layout (floats)
    float* ws = (float*)d_ws;
    float* dinv   = ws;                       // N
    float* norm   = dinv + N;                 // E
    float* bufA   = norm + E;                 // N*64
    float* bufB   = bufA + (size_t)N * HIDC;  // N*64
    float* pooled = bufB + (size_t)N * HIDC;  // G*64
    float* cnt    = pooled + (size_t)G * HIDC;// G

    const int BLK = 256;
    dim3 blk(BLK);
    int gN   = (N + BLK - 1) / BLK;
    int gE   = (E + BLK - 1) / BLK;
    int gN64 = ((size_t)N * HIDC + BLK - 1) / BLK;
    int gE16 = ((size_t)E * 16 + BLK - 1) / BLK;

    // degree + norm
    k_init_deg<<<gN, blk, 0, stream>>>(dinv, N);
    k_deg_accum<<<gE, blk, 0, stream>>>(col, ew, dinv, E);
    k_deg_to_dinv<<<gN, blk, 0, stream>>>(dinv, N);
    k_compute_norm<<<gE, blk, 0, stream>>>(row, col, ew, dinv, norm, E);

    // layer 1: h = x@W1 -> A ; agg -> B ; relu(B + b1)
    k_gemm_node<22><<<gN64, blk, 0, stream>>>(x, W1, bufA, N);
    k_agg_init<<<gN64, blk, 0, stream>>>(bufA, dinv, bufB, N);
    k_agg_edges<<<gE16, blk, 0, stream>>>(row, col, norm, bufA, bufB, E);
    k_bias_relu<<<gN64, blk, 0, stream>>>(bufB, b1, N);

    // layer 2: h2 = B@W2 -> A ; agg -> B ; relu(B + b2)
    k_gemm_node<64><<<gN64, blk, 0, stream>>>(bufB, W2, bufA, N);
    k_agg_init<<<gN64, blk, 0, stream>>>(bufA, dinv, bufB, N);
    k_agg_edges<<<gE16, blk, 0, stream>>>(row, col, norm, bufA, bufB, E);
    k_bias_relu<<<gN64, blk, 0, stream>>>(bufB, b2, N);

    // pool
    int zeroN = G * HIDC + G;   // pooled + cnt are contiguous
    k_zero<<<(zeroN + BLK - 1) / BLK, blk, 0, stream>>>(pooled, zeroN);
    k_pool<<<(N + 255) / 256, blk, 0, stream>>>(bufB, batch, pooled, N);
    {
        int nthr = (N + 63) / 64;
        k_count<<<(nthr + BLK - 1) / BLK, blk, 0, stream>>>(batch, cnt, N);
    }

    // head
    k_head<<<G, dim3(64), 0, stream>>>(pooled, cnt, fw1, fb1, fw2, fb2, out, NCLASS);
}

// Round 2
// 510.643 us; speedup vs baseline: 4.3577x; 4.3577x over previous
//
#include <hip/hip_runtime.h>
#include <hip/hip_bf16.h>

// GCN forward: 2x GCNConv(relu) -> global_mean_pool -> MLP head.
// Round 2: scatter-atomic aggregation replaced by on-device CSR build + gather.

#define HIDC 64
#define SCAN_CHUNK 1024   // elements scanned per block in k_scan_block

__global__ void k_init_deg(float* deg, int n) {
    int i = blockIdx.x * blockDim.x + threadIdx.x;
    if (i < n) deg[i] = 1.0f;   // self-loop weight
}

__global__ void k_zero_int(int* p, int n) {
    int i = blockIdx.x * blockDim.x + threadIdx.x;
    if (i < n) p[i] = 0;
}

// weighted in-degree (float) + in-edge count (int), one pass over edges
__global__ void k_edge_stats(const int* __restrict__ col, const float* __restrict__ w,
                             float* deg, int* cnt_in, int E) {
    int e = blockIdx.x * blockDim.x + threadIdx.x;
    if (e < E) {
        int c = col[e];
        atomicAdd(&deg[c], w[e]);
        atomicAdd(&cnt_in[c], 1);
    }
}

__global__ void k_deg_to_dinv(float* deg, int n) {
    int i = blockIdx.x * blockDim.x + threadIdx.x;
    if (i < n) deg[i] = rsqrtf(deg[i]);   // deg >= 1 always (self-loop)
}

// exclusive scan of cnt over SCAN_CHUNK-sized blocks; emits per-block sums
__global__ void k_scan_block(const int* __restrict__ cnt, int* __restrict__ off,
                             int* __restrict__ bsum, int n) {
    __shared__ int s[256];
    int t = threadIdx.x;
    int base = blockIdx.x * SCAN_CHUNK + t * 4;
    int v0 = (base + 0 < n) ? cnt[base + 0] : 0;
    int v1 = (base + 1 < n) ? cnt[base + 1] : 0;
    int v2 = (base + 2 < n) ? cnt[base + 2] : 0;
    int v3 = (base + 3 < n) ? cnt[base + 3] : 0;
    int sum = v0 + v1 + v2 + v3;
    s[t] = sum;
    __syncthreads();
    for (int o = 1; o < 256; o <<= 1) {
        int x = (t >= o) ? s[t - o] : 0;
        __syncthreads();
        s[t] += x;
        __syncthreads();
    }
    int ex = s[t] - sum;   // exclusive prefix within block
    if (t == 255) bsum[blockIdx.x] = s[255];
    if (base + 0 < n) off[base + 0] = ex; ex += v0;
    if (base + 1 < n) off[base + 1] = ex; ex += v1;
    if (base + 2 < n) off[base + 2] = ex; ex += v2;
    if (base + 3 < n) off[base + 3] = ex;
}

// single-block exclusive scan of the block sums (nb <= 256)
__global__ void k_scan_sums(int* bs, int nb) {
    __shared__ int s[256];
    int t = threadIdx.x;
    int v = (t < nb) ? bs[t] : 0;
    s[t] = v;
    __syncthreads();
    for (int o = 1; o < 256; o <<= 1) {
        int x = (t >= o) ? s[t - o] : 0;
        __syncthreads();
        s[t] += x;
        __syncthreads();
    }
    if (t < nb) bs[t] = s[t] - v;   // exclusive
}

// add scanned block sums; produce final offsets + cursor copy; off[n] = E
__global__ void k_scan_add(int* __restrict__ off, int* __restrict__ cursor,
                           const int* __restrict__ bs, int n, int E) {
    int i = blockIdx.x * blockDim.x + threadIdx.x;
    if (i < n) {
        int v = off[i] + bs[i >> 10];   // SCAN_CHUNK == 1024
        off[i] = v;
        cursor[i] = v;
    }
    if (i == 0) off[n] = E;
}

// place each edge into its destination's CSR slot; fold norm computation in
__global__ void k_scatter_csr(const int* __restrict__ row, const int* __restrict__ col,
                              const float* __restrict__ ew, const float* __restrict__ dinv,
                              int* cursor, int* __restrict__ csr_src, float* __restrict__ csr_w,
                              int E) {
    int e = blockIdx.x * blockDim.x + threadIdx.x;
    if (e >= E) return;
    int r = row[e], c = col[e];
    int p = atomicAdd(&cursor[c], 1);
    csr_src[p] = r;
    csr_w[p] = dinv[r] * ew[e] * dinv[c];
}

// h[n][64] = x[n][K] @ W[K][64]   (bias applied later, in the gather)
template <int K>
__global__ void k_gemm_node(const float* __restrict__ x, const float* __restrict__ W,
                            float* __restrict__ h, int n) {
    __shared__ float sW[K * HIDC];
    for (int i = threadIdx.x; i < K * HIDC; i += blockDim.x) sW[i] = W[i];
    __syncthreads();
    int t = blockIdx.x * blockDim.x + threadIdx.x;
    int node = t >> 6, c = t & 63;
    if (node >= n) return;
    const float* xr = x + (size_t)node * K;
    float acc = 0.f;
#pragma unroll
    for (int k = 0; k < K; ++k) acc = fmaf(xr[k], sW[k * HIDC + c], acc);
    h[(size_t)node * HIDC + c] = acc;
}

// One wave per node (lane = channel): self-loop + gather in-edges + bias + relu.
__global__ void k_gcn_gather(const float* __restrict__ h, const int* __restrict__ off,
                             const int* __restrict__ csr_src, const float* __restrict__ csr_w,
                             const float* __restrict__ dinv, const float* __restrict__ bias,
                             float* __restrict__ out, int n) {
    int node = (blockIdx.x * blockDim.x + threadIdx.x) >> 6;
    int lane = threadIdx.x & 63;
    if (node >= n) return;
    float d = dinv[node];
    float acc = d * d * h[(size_t)node * HIDC + lane];
    int i = off[node], s1 = off[node + 1];
    // 2-wide manual unroll: two independent gathers in flight
    for (; i + 1 < s1; i += 2) {
        int sA = csr_src[i], sB = csr_src[i + 1];
        float wA = csr_w[i], wB = csr_w[i + 1];
        float hA = h[(size_t)sA * HIDC + lane];
        float hB = h[(size_t)sB * HIDC + lane];
        acc = fmaf(wA, hA, acc);
        acc = fmaf(wB, hB, acc);
    }
    if (i < s1) {
        acc = fmaf(csr_w[i], h[(size_t)csr_src[i] * HIDC + lane], acc);
    }
    out[(size_t)node * HIDC + lane] = fmaxf(acc + bias[lane], 0.f);
}

__global__ void k_zero(float* p, int n) {
    int i = blockIdx.x * blockDim.x + threadIdx.x;
    if (i < n) p[i] = 0.f;
}

// batch is sorted: segmented accumulate, flush (atomic) only on graph change.
__global__ void k_pool(const float* __restrict__ h, const int* __restrict__ batch,
                       float* __restrict__ pooled, int n) {
    int c = threadIdx.x & 63, sub = threadIdx.x >> 6;
    int n0 = blockIdx.x * 256;
    int nend = min(n0 + 256, n);
    float acc = 0.f;
    int curb = -1;
    for (int i = n0 + sub; i < nend; i += 4) {
        int b = batch[i];
        if (b != curb) {
            if (curb >= 0) atomicAdd(&pooled[curb * HIDC + c], acc);
            acc = 0.f;
            curb = b;
        }
        acc += h[(size_t)i * HIDC + c];
    }
    if (curb >= 0) atomicAdd(&pooled[curb * HIDC + c], acc);
}

__global__ void k_count(const int* __restrict__ batch, float* __restrict__ cnt, int n) {
    int t = blockIdx.x * blockDim.x + threadIdx.x;
    int i0 = t * 64;
    if (i0 >= n) return;
    int end = min(i0 + 64, n);
    int curb = batch[i0];
    float acc = 0.f;
    for (int i = i0; i < end; ++i) {
        int b = batch[i];
        if (b != curb) {
            atomicAdd(&cnt[curb], acc);
            acc = 0.f;
            curb = b;
        }
        acc += 1.f;
    }
    atomicAdd(&cnt[curb], acc);
}

// One 64-thread block per graph: mean, fc1+relu, fc2.
__global__ void k_head(const float* __restrict__ pooled, const float* __restrict__ cnt,
                       const float* __restrict__ fw1, const float* __restrict__ fb1,
                       const float* __restrict__ fw2, const float* __restrict__ fb2,
                       float* __restrict__ out, int nclass) {
    int g = blockIdx.x;
    int j = threadIdx.x;   // 0..63
    __shared__ float p[HIDC], hid[HIDC];
    float c = fmaxf(cnt[g], 1.0f);
    p[j] = pooled[g * HIDC + j] / c;
    __syncthreads();
    float acc = fb1[j];
#pragma unroll 8
    for (int k = 0; k < HIDC; ++k) acc = fmaf(p[k], fw1[k * HIDC + j], acc);
    hid[j] = fmaxf(acc, 0.f);
    __syncthreads();
    if (j < nclass) {
        float o = fb2[j];
#pragma unroll 8
        for (int k = 0; k < HIDC; ++k) o = fmaf(hid[k], fw2[k * nclass + j], o);
        out[g * nclass + j] = o;
    }
}

extern "C" void kernel_launch(void* const* d_in, const int* in_sizes, int n_in,
                              void* d_out, int out_size, void* d_ws, size_t ws_size,
                              hipStream_t stream) {
    const float* x    = (const float*)d_in[0];
    const int* eidx   = (const int*)d_in[1];
    const float* ew   = (const float*)d_in[2];
    const int* batch  = (const int*)d_in[3];
    const float* W1   = (const float*)d_in[4];
    const float* b1   = (const float*)d_in[5];
    const float* W2   = (const float*)d_in[6];
    const float* b2   = (const float*)d_in[7];
    const float* fw1  = (const float*)d_in[8];
    const float* fb1  = (const float*)d_in[9];
    const float* fw2  = (const float*)d_in[10];
    const float* fb2  = (const float*)d_in[11];
    float* out = (float*)d_out;

    const int N = in_sizes[3];                // batch vector length
    const int E = in_sizes[1] / 2;            // edge_index is (2, E)
    const int NCLASS = in_sizes[11];          // fb2 length
    const int G = out_size / NCLASS;

    const int* row = eidx;
    const int* col = eidx + E;

    // ---- workspace layout ----
    char* wp = (char*)d_ws;
    float* dinv   = (float*)wp;  wp += sizeof(float) * N;
    float* bufA   = (float*)wp;  wp += sizeof(float) * (size_t)N * HIDC;
    float* bufB   = (float*)wp;  wp += sizeof(float) * (size_t)N * HIDC;
    float* pooled = (float*)wp;  wp += sizeof(float) * (size_t)G * HIDC;
    float* cnt    = (float*)wp;  wp += sizeof(float) * G;
    float* csr_w  = (float*)wp;  wp += sizeof(float) * E;
    int*   cnt_in = (int*)wp;    wp += sizeof(int) * N;      // reused as cursor
    int*   off    = (int*)wp;    wp += sizeof(int) * (N + 1);
    int*   bsum   = (int*)wp;    wp += sizeof(int) * 256;
    int*   csr_src= (int*)wp;    wp += sizeof(int) * E;
    int*   cursor = cnt_in;

    const int BLK = 256;
    dim3 blk(BLK);
    int gN   = (N + BLK - 1) / BLK;
    int gE   = (E + BLK - 1) / BLK;
    int gN64 = ((size_t)N * HIDC + BLK - 1) / BLK;
    int nScanBlocks = (N + SCAN_CHUNK - 1) / SCAN_CHUNK;   // <= 256 for N <= 262144

    // degree + in-degree counts
    k_init_deg<<<gN, blk, 0, stream>>>(dinv, N);
    k_zero_int<<<gN, blk, 0, stream>>>(cnt_in, N);
    k_edge_stats<<<gE, blk, 0, stream>>>(col, ew, dinv, cnt_in, E);
    k_deg_to_dinv<<<gN, blk, 0, stream>>>(dinv, N);

    // CSR by destination: scan counts -> offsets -> scatter (norm folded in)
    k_scan_block<<<nScanBlocks, blk, 0, stream>>>(cnt_in, off, bsum, N);
    k_scan_sums<<<1, blk, 0, stream>>>(bsum, nScanBlocks);
    k_scan_add<<<gN, blk, 0, stream>>>(off, cursor, bsum, N, E);
    k_scatter_csr<<<gE, blk, 0, stream>>>(row, col, ew, dinv, cursor, csr_src, csr_w, E);

    // layer 1: h = x@W1 -> A ; gather(A)+bias+relu -> B
    k_gemm_node<22><<<gN64, blk, 0, stream>>>(x, W1, bufA, N);
    k_gcn_gather<<<gN64, blk, 0, stream>>>(bufA, off, csr_src, csr_w, dinv, b1, bufB, N);

    // layer 2: h2 = B@W2 -> A ; gather(A)+bias+relu -> B
    k_gemm_node<64><<<gN64, blk, 0, stream>>>(bufB, W2, bufA, N);
    k_gcn_gather<<<gN64, blk, 0, stream>>>(bufA, off, csr_src, csr_w, dinv, b2, bufB, N);

    // pool
    int zeroN = G * HIDC + G;   // pooled + cnt are contiguous
    k_zero<<<(zeroN + BLK - 1) / BLK, blk, 0, stream>>>(pooled, zeroN);
    k_pool<<<(N + 255) / 256, blk, 0, stream>>>(bufB, batch, pooled, N);
    {
        int nthr = (N + 63) / 64;
        k_count<<<(nthr + BLK - 1) / BLK, blk, 0, stream>>>(batch, cnt, N);
    }

    // head
    k_head<<<G, dim3(64), 0, stream>>>(pooled, cnt, fw1, fb1, fw2, fb2, out, NCLASS);
}

// Round 3
// 457.172 us; speedup vs baseline: 4.8673x; 1.1170x over previous
//
#include <hip/hip_runtime.h>
#include <hip/hip_bf16.h>

// GCN forward: 2x GCNConv(relu) -> global_mean_pool -> MLP head.
// Round 3: packed u64 atomics for degree+count; packed u64 CSR entries;
//          fused unpack-into-scan and count-into-pool.

#define HIDC 64
#define SCAN_CHUNK 1024   // elements scanned per block in k_scan_block

typedef unsigned long long u64;
#define SUM_MASK ((1ULL << 48) - 1)   // low 48 bits: Q16.32 weighted degree
#define CNT_ONE  (1ULL << 48)         // high 16 bits: in-edge count

__global__ void k_init_packed(u64* p, int n) {
    int i = blockIdx.x * blockDim.x + threadIdx.x;
    if (i < n) p[i] = (1ULL << 32);   // deg = 1.0 (self-loop), count = 0
}

// one u64 atomic per edge: weighted in-degree (Q16.32) + in-edge count
__global__ void k_edge_stats(const int* __restrict__ col, const float* __restrict__ w,
                             u64* packed, int E) {
    int e = blockIdx.x * blockDim.x + threadIdx.x;
    if (e < E) {
        u64 add = (u64)((double)w[e] * 4294967296.0 + 0.5) | CNT_ONE;
        atomicAdd(&packed[col[e]], add);
    }
}

// exclusive scan of counts (from packed) over SCAN_CHUNK blocks; also emits dinv
__global__ void k_scan_block(const u64* __restrict__ packed, int* __restrict__ off,
                             int* __restrict__ bsum, float* __restrict__ dinv, int n) {
    __shared__ int s[256];
    int t = threadIdx.x;
    int base = blockIdx.x * SCAN_CHUNK + t * 4;
    int v0 = 0, v1 = 0, v2 = 0, v3 = 0;
#define LOADC(j, vj) \
    if (base + j < n) { \
        u64 p = packed[base + j]; \
        vj = (int)(p >> 48); \
        dinv[base + j] = rsqrtf((float)((double)(p & SUM_MASK) * 2.3283064365386963e-10)); \
    }
    LOADC(0, v0) LOADC(1, v1) LOADC(2, v2) LOADC(3, v3)
#undef LOADC
    int sum = v0 + v1 + v2 + v3;
    s[t] = sum;
    __syncthreads();
    for (int o = 1; o < 256; o <<= 1) {
        int x = (t >= o) ? s[t - o] : 0;
        __syncthreads();
        s[t] += x;
        __syncthreads();
    }
    int ex = s[t] - sum;   // exclusive prefix within block
    if (t == 255) bsum[blockIdx.x] = s[255];
    if (base + 0 < n) off[base + 0] = ex; ex += v0;
    if (base + 1 < n) off[base + 1] = ex; ex += v1;
    if (base + 2 < n) off[base + 2] = ex; ex += v2;
    if (base + 3 < n) off[base + 3] = ex;
}

// single-block exclusive scan of the block sums (nb <= 256)
__global__ void k_scan_sums(int* bs, int nb) {
    __shared__ int s[256];
    int t = threadIdx.x;
    int v = (t < nb) ? bs[t] : 0;
    s[t] = v;
    __syncthreads();
    for (int o = 1; o < 256; o <<= 1) {
        int x = (t >= o) ? s[t - o] : 0;
        __syncthreads();
        s[t] += x;
        __syncthreads();
    }
    if (t < nb) bs[t] = s[t] - v;   // exclusive
}

// add scanned block sums; produce final offsets + cursor copy; off[n] = E
__global__ void k_scan_add(int* __restrict__ off, int* __restrict__ cursor,
                           const int* __restrict__ bs, int n, int E) {
    int i = blockIdx.x * blockDim.x + threadIdx.x;
    if (i < n) {
        int v = off[i] + bs[i >> 10];   // SCAN_CHUNK == 1024
        off[i] = v;
        cursor[i] = v;
    }
    if (i == 0) off[n] = E;
}

// place each edge into its destination's CSR slot; entry = (src<<32)|bits(dinv[src]*ew)
__global__ void k_scatter_csr(const int* __restrict__ row, const int* __restrict__ col,
                              const float* __restrict__ ew, const float* __restrict__ dinv,
                              int* cursor, u64* __restrict__ csr, int E) {
    int e = blockIdx.x * blockDim.x + threadIdx.x;
    if (e >= E) return;
    int r = row[e], c = col[e];
    float wn = dinv[r] * ew[e];
    int p = atomicAdd(&cursor[c], 1);
    csr[p] = ((u64)(unsigned)r << 32) | (u64)__float_as_uint(wn);
}

// h[n][64] = x[n][K] @ W[K][64]   (bias applied later, in the gather)
template <int K>
__global__ void k_gemm_node(const float* __restrict__ x, const float* __restrict__ W,
                            float* __restrict__ h, int n) {
    __shared__ float sW[K * HIDC];
    for (int i = threadIdx.x; i < K * HIDC; i += blockDim.x) sW[i] = W[i];
    __syncthreads();
    int t = blockIdx.x * blockDim.x + threadIdx.x;
    int node = t >> 6, c = t & 63;
    if (node >= n) return;
    const float* xr = x + (size_t)node * K;
    float acc = 0.f;
#pragma unroll
    for (int k = 0; k < K; ++k) acc = fmaf(xr[k], sW[k * HIDC + c], acc);
    h[(size_t)node * HIDC + c] = acc;
}

// One wave per node (lane = channel): out = d*(sum_e w_e*h[src_e] + d*h_self) + b, relu.
__global__ void k_gcn_gather(const float* __restrict__ h, const int* __restrict__ off,
                             const u64* __restrict__ csr, const float* __restrict__ dinv,
                             const float* __restrict__ bias, float* __restrict__ out, int n) {
    int node = (blockIdx.x * blockDim.x + threadIdx.x) >> 6;
    int lane = threadIdx.x & 63;
    if (node >= n) return;
    float d = dinv[node];
    float acc = d * h[(size_t)node * HIDC + lane];
    int i = off[node], s1 = off[node + 1];
    for (; i + 1 < s1; i += 2) {
        u64 eA = csr[i], eB = csr[i + 1];
        int sA = (int)(eA >> 32), sB = (int)(eB >> 32);
        float wA = __uint_as_float((unsigned)eA);
        float wB = __uint_as_float((unsigned)eB);
        float hA = h[(size_t)sA * HIDC + lane];
        float hB = h[(size_t)sB * HIDC + lane];
        acc = fmaf(wA, hA, acc);
        acc = fmaf(wB, hB, acc);
    }
    if (i < s1) {
        u64 eA = csr[i];
        acc = fmaf(__uint_as_float((unsigned)eA), h[(size_t)(eA >> 32) * HIDC + lane], acc);
    }
    out[(size_t)node * HIDC + lane] = fmaxf(fmaf(d, acc, bias[lane]), 0.f);
}

__global__ void k_zero(float* p, int n) {
    int i = blockIdx.x * blockDim.x + threadIdx.x;
    if (i < n) p[i] = 0.f;
}

// batch is sorted: segmented accumulate, flush (atomic) only on graph change.
// Lane c==0 of each sub-group also accumulates node counts (fused k_count).
__global__ void k_pool(const float* __restrict__ h, const int* __restrict__ batch,
                       float* __restrict__ pooled, float* __restrict__ cnt, int n) {
    int c = threadIdx.x & 63, sub = threadIdx.x >> 6;
    int n0 = blockIdx.x * 256;
    int nend = min(n0 + 256, n);
    float acc = 0.f, cacc = 0.f;
    int curb = -1;
    for (int i = n0 + sub; i < nend; i += 4) {
        int b = batch[i];
        if (b != curb) {
            if (curb >= 0) {
                atomicAdd(&pooled[curb * HIDC + c], acc);
                if (c == 0) atomicAdd(&cnt[curb], cacc);
            }
            acc = 0.f; cacc = 0.f;
            curb = b;
        }
        acc += h[(size_t)i * HIDC + c];
        cacc += 1.f;
    }
    if (curb >= 0) {
        atomicAdd(&pooled[curb * HIDC + c], acc);
        if (c == 0) atomicAdd(&cnt[curb], cacc);
    }
}

// One 64-thread block per graph: mean, fc1+relu, fc2.
__global__ void k_head(const float* __restrict__ pooled, const float* __restrict__ cnt,
                       const float* __restrict__ fw1, const float* __restrict__ fb1,
                       const float* __restrict__ fw2, const float* __restrict__ fb2,
                       float* __restrict__ out, int nclass) {
    int g = blockIdx.x;
    int j = threadIdx.x;   // 0..63
    __shared__ float p[HIDC], hid[HIDC];
    float c = fmaxf(cnt[g], 1.0f);
    p[j] = pooled[g * HIDC + j] / c;
    __syncthreads();
    float acc = fb1[j];
#pragma unroll 8
    for (int k = 0; k < HIDC; ++k) acc = fmaf(p[k], fw1[k * HIDC + j], acc);
    hid[j] = fmaxf(acc, 0.f);
    __syncthreads();
    if (j < nclass) {
        float o = fb2[j];
#pragma unroll 8
        for (int k = 0; k < HIDC; ++k) o = fmaf(hid[k], fw2[k * nclass + j], o);
        out[g * nclass + j] = o;
    }
}

extern "C" void kernel_launch(void* const* d_in, const int* in_sizes, int n_in,
                              void* d_out, int out_size, void* d_ws, size_t ws_size,
                              hipStream_t stream) {
    const float* x    = (const float*)d_in[0];
    const int* eidx   = (const int*)d_in[1];
    const float* ew   = (const float*)d_in[2];
    const int* batch  = (const int*)d_in[3];
    const float* W1   = (const float*)d_in[4];
    const float* b1   = (const float*)d_in[5];
    const float* W2   = (const float*)d_in[6];
    const float* b2   = (const float*)d_in[7];
    const float* fw1  = (const float*)d_in[8];
    const float* fb1  = (const float*)d_in[9];
    const float* fw2  = (const float*)d_in[10];
    const float* fb2  = (const float*)d_in[11];
    float* out = (float*)d_out;

    const int N = in_sizes[3];                // batch vector length
    const int E = in_sizes[1] / 2;            // edge_index is (2, E)
    const int NCLASS = in_sizes[11];          // fb2 length
    const int G = out_size / NCLASS;

    const int* row = eidx;
    const int* col = eidx + E;

    // ---- workspace layout (8B-aligned arrays first) ----
    char* wp = (char*)d_ws;
    u64*   packed = (u64*)wp;    wp += sizeof(u64) * N;
    u64*   csr    = (u64*)wp;    wp += sizeof(u64) * E;
    float* dinv   = (float*)wp;  wp += sizeof(float) * N;
    float* bufA   = (float*)wp;  wp += sizeof(float) * (size_t)N * HIDC;
    float* bufB   = (float*)wp;  wp += sizeof(float) * (size_t)N * HIDC;
    float* pooled = (float*)wp;  wp += sizeof(float) * (size_t)G * HIDC;
    float* cnt    = (float*)wp;  wp += sizeof(float) * G;
    int*   off    = (int*)wp;    wp += sizeof(int) * (N + 1);
    int*   cursor = (int*)wp;    wp += sizeof(int) * N;
    int*   bsum   = (int*)wp;    wp += sizeof(int) * 256;

    const int BLK = 256;
    dim3 blk(BLK);
    int gN   = (N + BLK - 1) / BLK;
    int gE   = (E + BLK - 1) / BLK;
    int gN64 = ((size_t)N * HIDC + BLK - 1) / BLK;
    int nScanBlocks = (N + SCAN_CHUNK - 1) / SCAN_CHUNK;   // <= 256 for N <= 262144

    // packed degree/count accumulation
    k_init_packed<<<gN, blk, 0, stream>>>(packed, N);
    k_edge_stats<<<gE, blk, 0, stream>>>(col, ew, packed, E);

    // CSR by destination: scan counts (+dinv) -> offsets -> scatter
    k_scan_block<<<nScanBlocks, blk, 0, stream>>>(packed, off, bsum, dinv, N);
    k_scan_sums<<<1, blk, 0, stream>>>(bsum, nScanBlocks);
    k_scan_add<<<gN, blk, 0, stream>>>(off, cursor, bsum, N, E);
    k_scatter_csr<<<gE, blk, 0, stream>>>(row, col, ew, dinv, cursor, csr, E);

    // layer 1: h = x@W1 -> A ; gather(A)+bias+relu -> B
    k_gemm_node<22><<<gN64, blk, 0, stream>>>(x, W1, bufA, N);
    k_gcn_gather<<<gN64, blk, 0, stream>>>(bufA, off, csr, dinv, b1, bufB, N);

    // layer 2: h2 = B@W2 -> A ; gather(A)+bias+relu -> B
    k_gemm_node<64><<<gN64, blk, 0, stream>>>(bufB, W2, bufA, N);
    k_gcn_gather<<<gN64, blk, 0, stream>>>(bufA, off, csr, dinv, b2, bufB, N);

    // pool (count fused)
    int zeroN = G * HIDC + G;   // pooled + cnt are contiguous
    k_zero<<<(zeroN + BLK - 1) / BLK, blk, 0, stream>>>(pooled, zeroN);
    k_pool<<<(N + 255) / 256, blk, 0, stream>>>(bufB, batch, pooled, cnt, N);

    // head
    k_head<<<G, dim3(64), 0, stream>>>(pooled, cnt, fw1, fb1, fw2, fb2, out, NCLASS);
}

// Round 4
// 377.493 us; speedup vs baseline: 5.8947x; 1.2111x over previous
//
#include <hip/hip_runtime.h>
#include <hip/hip_bf16.h>

// GCN forward: 2x GCNConv(relu) -> global_mean_pool -> MLP head.
// Round 4: register-blocked LDS-tiled node GEMM (8x4 acc per thread) replacing
//          the wave-per-node GEMM. CSR build unchanged.

#define HIDC 64
#define SCAN_CHUNK 1024
#define MTILE 128
#define XS_STRIDE (MTILE + 4)   // 132 floats; row byte-pitch 528 = 16B-aligned, pad breaks bank cycles

typedef unsigned long long u64;
#define SUM_MASK ((1ULL << 48) - 1)   // low 48 bits: Q16.32 weighted degree
#define CNT_ONE  (1ULL << 48)         // high 16 bits: in-edge count

__global__ void k_init_packed(u64* p, int n) {
    int i = blockIdx.x * blockDim.x + threadIdx.x;
    if (i < n) p[i] = (1ULL << 32);   // deg = 1.0 (self-loop), count = 0
}

// one u64 atomic per edge: weighted in-degree (Q16.32) + in-edge count
__global__ void k_edge_stats(const int* __restrict__ col, const float* __restrict__ w,
                             u64* packed, int E) {
    int e = blockIdx.x * blockDim.x + threadIdx.x;
    if (e < E) {
        u64 add = (u64)((double)w[e] * 4294967296.0 + 0.5) | CNT_ONE;
        atomicAdd(&packed[col[e]], add);
    }
}

// exclusive scan of counts (from packed) over SCAN_CHUNK blocks; also emits dinv
__global__ void k_scan_block(const u64* __restrict__ packed, int* __restrict__ off,
                             int* __restrict__ bsum, float* __restrict__ dinv, int n) {
    __shared__ int s[256];
    int t = threadIdx.x;
    int base = blockIdx.x * SCAN_CHUNK + t * 4;
    int v0 = 0, v1 = 0, v2 = 0, v3 = 0;
#define LOADC(j, vj) \
    if (base + j < n) { \
        u64 p = packed[base + j]; \
        vj = (int)(p >> 48); \
        dinv[base + j] = rsqrtf((float)((double)(p & SUM_MASK) * 2.3283064365386963e-10)); \
    }
    LOADC(0, v0) LOADC(1, v1) LOADC(2, v2) LOADC(3, v3)
#undef LOADC
    int sum = v0 + v1 + v2 + v3;
    s[t] = sum;
    __syncthreads();
    for (int o = 1; o < 256; o <<= 1) {
        int x = (t >= o) ? s[t - o] : 0;
        __syncthreads();
        s[t] += x;
        __syncthreads();
    }
    int ex = s[t] - sum;   // exclusive prefix within block
    if (t == 255) bsum[blockIdx.x] = s[255];
    if (base + 0 < n) off[base + 0] = ex; ex += v0;
    if (base + 1 < n) off[base + 1] = ex; ex += v1;
    if (base + 2 < n) off[base + 2] = ex; ex += v2;
    if (base + 3 < n) off[base + 3] = ex;
}

// single-block exclusive scan of the block sums (nb <= 256)
__global__ void k_scan_sums(int* bs, int nb) {
    __shared__ int s[256];
    int t = threadIdx.x;
    int v = (t < nb) ? bs[t] : 0;
    s[t] = v;
    __syncthreads();
    for (int o = 1; o < 256; o <<= 1) {
        int x = (t >= o) ? s[t - o] : 0;
        __syncthreads();
        s[t] += x;
        __syncthreads();
    }
    if (t < nb) bs[t] = s[t] - v;   // exclusive
}

// add scanned block sums; produce final offsets + cursor copy; off[n] = E
__global__ void k_scan_add(int* __restrict__ off, int* __restrict__ cursor,
                           const int* __restrict__ bs, int n, int E) {
    int i = blockIdx.x * blockDim.x + threadIdx.x;
    if (i < n) {
        int v = off[i] + bs[i >> 10];   // SCAN_CHUNK == 1024
        off[i] = v;
        cursor[i] = v;
    }
    if (i == 0) off[n] = E;
}

// place each edge into its destination's CSR slot; entry = (src<<32)|bits(dinv[src]*ew)
__global__ void k_scatter_csr(const int* __restrict__ row, const int* __restrict__ col,
                              const float* __restrict__ ew, const float* __restrict__ dinv,
                              int* cursor, u64* __restrict__ csr, int E) {
    int e = blockIdx.x * blockDim.x + threadIdx.x;
    if (e >= E) return;
    int r = row[e], c = col[e];
    float wn = dinv[r] * ew[e];
    int p = atomicAdd(&cursor[c], 1);
    csr[p] = ((u64)(unsigned)r << 32) | (u64)__float_as_uint(wn);
}

// Tiled GEMM: h[n][64] = x[n][K] @ W[K][64]. 128-node tile, x transposed in LDS,
// each thread owns an 8-node x 4-channel accumulator block.
template <int K>
__global__ __launch_bounds__(256) void k_gemm_tile(const float* __restrict__ x,
                                                   const float* __restrict__ W,
                                                   float* __restrict__ h, int n) {
    __shared__ float xs[K * XS_STRIDE];   // [K][MTILE] transposed, padded
    __shared__ float ws[K * HIDC];        // [K][64]
    int tid = threadIdx.x;
    int n0 = blockIdx.x * MTILE;

    for (int i = tid; i < K * HIDC; i += 256) ws[i] = W[i];

    if constexpr ((K & 3) == 0) {
        constexpr int KQ = K / 4;
        for (int i = tid; i < MTILE * KQ; i += 256) {
            int r = i / KQ, kq = i - r * KQ;
            float4 v = make_float4(0.f, 0.f, 0.f, 0.f);
            if (n0 + r < n)
                v = *reinterpret_cast<const float4*>(x + (size_t)(n0 + r) * K + kq * 4);
            int k0 = kq * 4;
            xs[(k0 + 0) * XS_STRIDE + r] = v.x;
            xs[(k0 + 1) * XS_STRIDE + r] = v.y;
            xs[(k0 + 2) * XS_STRIDE + r] = v.z;
            xs[(k0 + 3) * XS_STRIDE + r] = v.w;
        }
    } else {
        for (int i = tid; i < MTILE * K; i += 256) {
            int r = i / K, k = i - r * K;
            float v = (n0 + r < n) ? x[(size_t)(n0 + r) * K + k] : 0.f;
            xs[k * XS_STRIDE + r] = v;
        }
    }
    __syncthreads();

    int c0 = (tid & 15) * 4;    // channel group (16 groups x 4 ch)
    int m0 = (tid >> 4) * 8;    // node group within tile (16 groups x 8 nodes)
    float acc[8][4];
#pragma unroll
    for (int j = 0; j < 8; ++j)
#pragma unroll
        for (int q = 0; q < 4; ++q) acc[j][q] = 0.f;

#pragma unroll 4
    for (int k = 0; k < K; ++k) {
        float4 a0 = *reinterpret_cast<const float4*>(&xs[k * XS_STRIDE + m0]);
        float4 a1 = *reinterpret_cast<const float4*>(&xs[k * XS_STRIDE + m0 + 4]);
        float4 b  = *reinterpret_cast<const float4*>(&ws[k * HIDC + c0]);
        float av[8] = {a0.x, a0.y, a0.z, a0.w, a1.x, a1.y, a1.z, a1.w};
        float bv[4] = {b.x, b.y, b.z, b.w};
#pragma unroll
        for (int j = 0; j < 8; ++j)
#pragma unroll
            for (int q = 0; q < 4; ++q)
                acc[j][q] = fmaf(av[j], bv[q], acc[j][q]);
    }

#pragma unroll
    for (int j = 0; j < 8; ++j) {
        int node = n0 + m0 + j;
        if (node < n) {
            float4 v = make_float4(acc[j][0], acc[j][1], acc[j][2], acc[j][3]);
            *reinterpret_cast<float4*>(h + (size_t)node * HIDC + c0) = v;
        }
    }
}

// One wave per node (lane = channel): out = d*(sum_e w_e*h[src_e] + d*h_self) + b, relu.
__global__ void k_gcn_gather(const float* __restrict__ h, const int* __restrict__ off,
                             const u64* __restrict__ csr, const float* __restrict__ dinv,
                             const float* __restrict__ bias, float* __restrict__ out, int n) {
    int node = (blockIdx.x * blockDim.x + threadIdx.x) >> 6;
    int lane = threadIdx.x & 63;
    if (node >= n) return;
    float d = dinv[node];
    float acc = d * h[(size_t)node * HIDC + lane];
    int i = off[node], s1 = off[node + 1];
    for (; i + 1 < s1; i += 2) {
        u64 eA = csr[i], eB = csr[i + 1];
        int sA = (int)(eA >> 32), sB = (int)(eB >> 32);
        float wA = __uint_as_float((unsigned)eA);
        float wB = __uint_as_float((unsigned)eB);
        float hA = h[(size_t)sA * HIDC + lane];
        float hB = h[(size_t)sB * HIDC + lane];
        acc = fmaf(wA, hA, acc);
        acc = fmaf(wB, hB, acc);
    }
    if (i < s1) {
        u64 eA = csr[i];
        acc = fmaf(__uint_as_float((unsigned)eA), h[(size_t)(eA >> 32) * HIDC + lane], acc);
    }
    out[(size_t)node * HIDC + lane] = fmaxf(fmaf(d, acc, bias[lane]), 0.f);
}

__global__ void k_zero(float* p, int n) {
    int i = blockIdx.x * blockDim.x + threadIdx.x;
    if (i < n) p[i] = 0.f;
}

// batch is sorted: segmented accumulate, flush (atomic) only on graph change.
__global__ void k_pool(const float* __restrict__ h, const int* __restrict__ batch,
                       float* __restrict__ pooled, float* __restrict__ cnt, int n) {
    int c = threadIdx.x & 63, sub = threadIdx.x >> 6;
    int n0 = blockIdx.x * 256;
    int nend = min(n0 + 256, n);
    float acc = 0.f, cacc = 0.f;
    int curb = -1;
    for (int i = n0 + sub; i < nend; i += 4) {
        int b = batch[i];
        if (b != curb) {
            if (curb >= 0) {
                atomicAdd(&pooled[curb * HIDC + c], acc);
                if (c == 0) atomicAdd(&cnt[curb], cacc);
            }
            acc = 0.f; cacc = 0.f;
            curb = b;
        }
        acc += h[(size_t)i * HIDC + c];
        cacc += 1.f;
    }
    if (curb >= 0) {
        atomicAdd(&pooled[curb * HIDC + c], acc);
        if (c == 0) atomicAdd(&cnt[curb], cacc);
    }
}

// One 64-thread block per graph: mean, fc1+relu, fc2.
__global__ void k_head(const float* __restrict__ pooled, const float* __restrict__ cnt,
                       const float* __restrict__ fw1, const float* __restrict__ fb1,
                       const float* __restrict__ fw2, const float* __restrict__ fb2,
                       float* __restrict__ out, int nclass) {
    int g = blockIdx.x;
    int j = threadIdx.x;   // 0..63
    __shared__ float p[HIDC], hid[HIDC];
    float c = fmaxf(cnt[g], 1.0f);
    p[j] = pooled[g * HIDC + j] / c;
    __syncthreads();
    float acc = fb1[j];
#pragma unroll 8
    for (int k = 0; k < HIDC; ++k) acc = fmaf(p[k], fw1[k * HIDC + j], acc);
    hid[j] = fmaxf(acc, 0.f);
    __syncthreads();
    if (j < nclass) {
        float o = fb2[j];
#pragma unroll 8
        for (int k = 0; k < HIDC; ++k) o = fmaf(hid[k], fw2[k * nclass + j], o);
        out[g * nclass + j] = o;
    }
}

extern "C" void kernel_launch(void* const* d_in, const int* in_sizes, int n_in,
                              void* d_out, int out_size, void* d_ws, size_t ws_size,
                              hipStream_t stream) {
    const float* x    = (const float*)d_in[0];
    const int* eidx   = (const int*)d_in[1];
    const float* ew   = (const float*)d_in[2];
    const int* batch  = (const int*)d_in[3];
    const float* W1   = (const float*)d_in[4];
    const float* b1   = (const float*)d_in[5];
    const float* W2   = (const float*)d_in[6];
    const float* b2   = (const float*)d_in[7];
    const float* fw1  = (const float*)d_in[8];
    const float* fb1  = (const float*)d_in[9];
    const float* fw2  = (const float*)d_in[10];
    const float* fb2  = (const float*)d_in[11];
    float* out = (float*)d_out;

    const int N = in_sizes[3];                // batch vector length
    const int E = in_sizes[1] / 2;            // edge_index is (2, E)
    const int NCLASS = in_sizes[11];          // fb2 length
    const int G = out_size / NCLASS;

    const int* row = eidx;
    const int* col = eidx + E;

    // ---- workspace layout (8B-aligned arrays first) ----
    char* wp = (char*)d_ws;
    u64*   packed = (u64*)wp;    wp += sizeof(u64) * N;
    u64*   csr    = (u64*)wp;    wp += sizeof(u64) * E;
    float* dinv   = (float*)wp;  wp += sizeof(float) * N;
    float* bufA   = (float*)wp;  wp += sizeof(float) * (size_t)N * HIDC;
    float* bufB   = (float*)wp;  wp += sizeof(float) * (size_t)N * HIDC;
    float* pooled = (float*)wp;  wp += sizeof(float) * (size_t)G * HIDC;
    float* cnt    = (float*)wp;  wp += sizeof(float) * G;
    int*   off    = (int*)wp;    wp += sizeof(int) * (N + 1);
    int*   cursor = (int*)wp;    wp += sizeof(int) * N;
    int*   bsum   = (int*)wp;    wp += sizeof(int) * 256;

    const int BLK = 256;
    dim3 blk(BLK);
    int gN   = (N + BLK - 1) / BLK;
    int gE   = (E + BLK - 1) / BLK;
    int gN64 = ((size_t)N * HIDC + BLK - 1) / BLK;
    int gTile = (N + MTILE - 1) / MTILE;
    int nScanBlocks = (N + SCAN_CHUNK - 1) / SCAN_CHUNK;   // <= 256 for N <= 262144

    // packed degree/count accumulation
    k_init_packed<<<gN, blk, 0, stream>>>(packed, N);
    k_edge_stats<<<gE, blk, 0, stream>>>(col, ew, packed, E);

    // CSR by destination: scan counts (+dinv) -> offsets -> scatter
    k_scan_block<<<nScanBlocks, blk, 0, stream>>>(packed, off, bsum, dinv, N);
    k_scan_sums<<<1, blk, 0, stream>>>(bsum, nScanBlocks);
    k_scan_add<<<gN, blk, 0, stream>>>(off, cursor, bsum, N, E);
    k_scatter_csr<<<gE, blk, 0, stream>>>(row, col, ew, dinv, cursor, csr, E);

    // layer 1: h = x@W1 -> A ; gather(A)+bias+relu -> B
    k_gemm_tile<22><<<gTile, blk, 0, stream>>>(x, W1, bufA, N);
    k_gcn_gather<<<gN64, blk, 0, stream>>>(bufA, off, csr, dinv, b1, bufB, N);

    // layer 2: h2 = B@W2 -> A ; gather(A)+bias+relu -> B
    k_gemm_tile<64><<<gTile, blk, 0, stream>>>(bufB, W2, bufA, N);
    k_gcn_gather<<<gN64, blk, 0, stream>>>(bufA, off, csr, dinv, b2, bufB, N);

    // pool (count fused)
    int zeroN = G * HIDC + G;   // pooled + cnt are contiguous
    k_zero<<<(zeroN + BLK - 1) / BLK, blk, 0, stream>>>(pooled, zeroN);
    k_pool<<<(N + 255) / 256, blk, 0, stream>>>(bufB, batch, pooled, cnt, N);

    // head
    k_head<<<G, dim3(64), 0, stream>>>(pooled, cnt, fw1, fb1, fw2, fb2, out, NCLASS);
}

// Round 5
// 364.526 us; speedup vs baseline: 6.1044x; 1.0356x over previous
//
#include <hip/hip_runtime.h>
#include <hip/hip_bf16.h>
#include <hip/hip_fp16.h>

// GCN forward: 2x GCNConv(relu) -> global_mean_pool -> MLP head.
// Round 5: pre-aggregation features stored fp16 (halves random-gather traffic).
//          All arithmetic fp32; one RNE rounding per layer.

#define HIDC 64
#define SCAN_CHUNK 1024
#define MTILE 128
#define XS_STRIDE (MTILE + 4)

typedef unsigned long long u64;
#define SUM_MASK ((1ULL << 48) - 1)   // low 48 bits: Q16.32 weighted degree
#define CNT_ONE  (1ULL << 48)         // high 16 bits: in-edge count

__global__ void k_init_packed(u64* p, int n) {
    int i = blockIdx.x * blockDim.x + threadIdx.x;
    if (i < n) p[i] = (1ULL << 32);   // deg = 1.0 (self-loop), count = 0
}

// one u64 atomic per edge: weighted in-degree (Q16.32) + in-edge count
__global__ void k_edge_stats(const int* __restrict__ col, const float* __restrict__ w,
                             u64* packed, int E) {
    int e = blockIdx.x * blockDim.x + threadIdx.x;
    if (e < E) {
        u64 add = (u64)((double)w[e] * 4294967296.0 + 0.5) | CNT_ONE;
        atomicAdd(&packed[col[e]], add);
    }
}

// exclusive scan of counts (from packed) over SCAN_CHUNK blocks; also emits dinv
__global__ void k_scan_block(const u64* __restrict__ packed, int* __restrict__ off,
                             int* __restrict__ bsum, float* __restrict__ dinv, int n) {
    __shared__ int s[256];
    int t = threadIdx.x;
    int base = blockIdx.x * SCAN_CHUNK + t * 4;
    int v0 = 0, v1 = 0, v2 = 0, v3 = 0;
#define LOADC(j, vj) \
    if (base + j < n) { \
        u64 p = packed[base + j]; \
        vj = (int)(p >> 48); \
        dinv[base + j] = rsqrtf((float)((double)(p & SUM_MASK) * 2.3283064365386963e-10)); \
    }
    LOADC(0, v0) LOADC(1, v1) LOADC(2, v2) LOADC(3, v3)
#undef LOADC
    int sum = v0 + v1 + v2 + v3;
    s[t] = sum;
    __syncthreads();
    for (int o = 1; o < 256; o <<= 1) {
        int x = (t >= o) ? s[t - o] : 0;
        __syncthreads();
        s[t] += x;
        __syncthreads();
    }
    int ex = s[t] - sum;   // exclusive prefix within block
    if (t == 255) bsum[blockIdx.x] = s[255];
    if (base + 0 < n) off[base + 0] = ex; ex += v0;
    if (base + 1 < n) off[base + 1] = ex; ex += v1;
    if (base + 2 < n) off[base + 2] = ex; ex += v2;
    if (base + 3 < n) off[base + 3] = ex;
}

// single-block exclusive scan of the block sums (nb <= 256)
__global__ void k_scan_sums(int* bs, int nb) {
    __shared__ int s[256];
    int t = threadIdx.x;
    int v = (t < nb) ? bs[t] : 0;
    s[t] = v;
    __syncthreads();
    for (int o = 1; o < 256; o <<= 1) {
        int x = (t >= o) ? s[t - o] : 0;
        __syncthreads();
        s[t] += x;
        __syncthreads();
    }
    if (t < nb) bs[t] = s[t] - v;   // exclusive
}

// add scanned block sums; produce final offsets + cursor copy; off[n] = E
__global__ void k_scan_add(int* __restrict__ off, int* __restrict__ cursor,
                           const int* __restrict__ bs, int n, int E) {
    int i = blockIdx.x * blockDim.x + threadIdx.x;
    if (i < n) {
        int v = off[i] + bs[i >> 10];   // SCAN_CHUNK == 1024
        off[i] = v;
        cursor[i] = v;
    }
    if (i == 0) off[n] = E;
}

// place each edge into its destination's CSR slot; entry = (src<<32)|bits(dinv[src]*ew)
__global__ void k_scatter_csr(const int* __restrict__ row, const int* __restrict__ col,
                              const float* __restrict__ ew, const float* __restrict__ dinv,
                              int* cursor, u64* __restrict__ csr, int E) {
    int e = blockIdx.x * blockDim.x + threadIdx.x;
    if (e >= E) return;
    int r = row[e], c = col[e];
    float wn = dinv[r] * ew[e];
    int p = atomicAdd(&cursor[c], 1);
    csr[p] = ((u64)(unsigned)r << 32) | (u64)__float_as_uint(wn);
}

// Tiled GEMM: h[n][64] = x[n][K] @ W[K][64], output fp16 (RNE).
template <int K>
__global__ __launch_bounds__(256) void k_gemm_tile(const float* __restrict__ x,
                                                   const float* __restrict__ W,
                                                   __half* __restrict__ h, int n) {
    __shared__ float xs[K * XS_STRIDE];   // [K][MTILE] transposed, padded
    __shared__ float ws[K * HIDC];        // [K][64]
    int tid = threadIdx.x;
    int n0 = blockIdx.x * MTILE;

    for (int i = tid; i < K * HIDC; i += 256) ws[i] = W[i];

    if constexpr ((K & 3) == 0) {
        constexpr int KQ = K / 4;
        for (int i = tid; i < MTILE * KQ; i += 256) {
            int r = i / KQ, kq = i - r * KQ;
            float4 v = make_float4(0.f, 0.f, 0.f, 0.f);
            if (n0 + r < n)
                v = *reinterpret_cast<const float4*>(x + (size_t)(n0 + r) * K + kq * 4);
            int k0 = kq * 4;
            xs[(k0 + 0) * XS_STRIDE + r] = v.x;
            xs[(k0 + 1) * XS_STRIDE + r] = v.y;
            xs[(k0 + 2) * XS_STRIDE + r] = v.z;
            xs[(k0 + 3) * XS_STRIDE + r] = v.w;
        }
    } else {
        for (int i = tid; i < MTILE * K; i += 256) {
            int r = i / K, k = i - r * K;
            float v = (n0 + r < n) ? x[(size_t)(n0 + r) * K + k] : 0.f;
            xs[k * XS_STRIDE + r] = v;
        }
    }
    __syncthreads();

    int c0 = (tid & 15) * 4;    // channel group (16 groups x 4 ch)
    int m0 = (tid >> 4) * 8;    // node group within tile (16 groups x 8 nodes)
    float acc[8][4];
#pragma unroll
    for (int j = 0; j < 8; ++j)
#pragma unroll
        for (int q = 0; q < 4; ++q) acc[j][q] = 0.f;

#pragma unroll 4
    for (int k = 0; k < K; ++k) {
        float4 a0 = *reinterpret_cast<const float4*>(&xs[k * XS_STRIDE + m0]);
        float4 a1 = *reinterpret_cast<const float4*>(&xs[k * XS_STRIDE + m0 + 4]);
        float4 b  = *reinterpret_cast<const float4*>(&ws[k * HIDC + c0]);
        float av[8] = {a0.x, a0.y, a0.z, a0.w, a1.x, a1.y, a1.z, a1.w};
        float bv[4] = {b.x, b.y, b.z, b.w};
#pragma unroll
        for (int j = 0; j < 8; ++j)
#pragma unroll
            for (int q = 0; q < 4; ++q)
                acc[j][q] = fmaf(av[j], bv[q], acc[j][q]);
    }

#pragma unroll
    for (int j = 0; j < 8; ++j) {
        int node = n0 + m0 + j;
        if (node < n) {
            union { struct { __half2 a, b; } h2; float2 f2; } u;
            u.h2.a = __floats2half2_rn(acc[j][0], acc[j][1]);
            u.h2.b = __floats2half2_rn(acc[j][2], acc[j][3]);
            *reinterpret_cast<float2*>(h + (size_t)node * HIDC + c0) = u.f2;
        }
    }
}

// One wave per node (lane = channel): out = d*(sum_e w_e*h[src_e] + d*h_self) + b, relu.
// h is fp16 (128B rows); output fp32.
__global__ void k_gcn_gather(const __half* __restrict__ h, const int* __restrict__ off,
                             const u64* __restrict__ csr, const float* __restrict__ dinv,
                             const float* __restrict__ bias, float* __restrict__ out, int n) {
    int node = (blockIdx.x * blockDim.x + threadIdx.x) >> 6;
    int lane = threadIdx.x & 63;
    if (node >= n) return;
    float d = dinv[node];
    float acc = d * __half2float(h[(size_t)node * HIDC + lane]);
    int i = off[node], s1 = off[node + 1];
    for (; i + 1 < s1; i += 2) {
        u64 eA = csr[i], eB = csr[i + 1];
        int sA = (int)(eA >> 32), sB = (int)(eB >> 32);
        float wA = __uint_as_float((unsigned)eA);
        float wB = __uint_as_float((unsigned)eB);
        float hA = __half2float(h[(size_t)sA * HIDC + lane]);
        float hB = __half2float(h[(size_t)sB * HIDC + lane]);
        acc = fmaf(wA, hA, acc);
        acc = fmaf(wB, hB, acc);
    }
    if (i < s1) {
        u64 eA = csr[i];
        acc = fmaf(__uint_as_float((unsigned)eA),
                   __half2float(h[(size_t)(eA >> 32) * HIDC + lane]), acc);
    }
    out[(size_t)node * HIDC + lane] = fmaxf(fmaf(d, acc, bias[lane]), 0.f);
}

__global__ void k_zero(float* p, int n) {
    int i = blockIdx.x * blockDim.x + threadIdx.x;
    if (i < n) p[i] = 0.f;
}

// batch is sorted: segmented accumulate, flush (atomic) only on graph change.
__global__ void k_pool(const float* __restrict__ h, const int* __restrict__ batch,
                       float* __restrict__ pooled, float* __restrict__ cnt, int n) {
    int c = threadIdx.x & 63, sub = threadIdx.x >> 6;
    int n0 = blockIdx.x * 256;
    int nend = min(n0 + 256, n);
    float acc = 0.f, cacc = 0.f;
    int curb = -1;
    for (int i = n0 + sub; i < nend; i += 4) {
        int b = batch[i];
        if (b != curb) {
            if (curb >= 0) {
                atomicAdd(&pooled[curb * HIDC + c], acc);
                if (c == 0) atomicAdd(&cnt[curb], cacc);
            }
            acc = 0.f; cacc = 0.f;
            curb = b;
        }
        acc += h[(size_t)i * HIDC + c];
        cacc += 1.f;
    }
    if (curb >= 0) {
        atomicAdd(&pooled[curb * HIDC + c], acc);
        if (c == 0) atomicAdd(&cnt[curb], cacc);
    }
}

// One 64-thread block per graph: mean, fc1+relu, fc2.
__global__ void k_head(const float* __restrict__ pooled, const float* __restrict__ cnt,
                       const float* __restrict__ fw1, const float* __restrict__ fb1,
                       const float* __restrict__ fw2, const float* __restrict__ fb2,
                       float* __restrict__ out, int nclass) {
    int g = blockIdx.x;
    int j = threadIdx.x;   // 0..63
    __shared__ float p[HIDC], hid[HIDC];
    float c = fmaxf(cnt[g], 1.0f);
    p[j] = pooled[g * HIDC + j] / c;
    __syncthreads();
    float acc = fb1[j];
#pragma unroll 8
    for (int k = 0; k < HIDC; ++k) acc = fmaf(p[k], fw1[k * HIDC + j], acc);
    hid[j] = fmaxf(acc, 0.f);
    __syncthreads();
    if (j < nclass) {
        float o = fb2[j];
#pragma unroll 8
        for (int k = 0; k < HIDC; ++k) o = fmaf(hid[k], fw2[k * nclass + j], o);
        out[g * nclass + j] = o;
    }
}

extern "C" void kernel_launch(void* const* d_in, const int* in_sizes, int n_in,
                              void* d_out, int out_size, void* d_ws, size_t ws_size,
                              hipStream_t stream) {
    const float* x    = (const float*)d_in[0];
    const int* eidx   = (const int*)d_in[1];
    const float* ew   = (const float*)d_in[2];
    const int* batch  = (const int*)d_in[3];
    const float* W1   = (const float*)d_in[4];
    const float* b1   = (const float*)d_in[5];
    const float* W2   = (const float*)d_in[6];
    const float* b2   = (const float*)d_in[7];
    const float* fw1  = (const float*)d_in[8];
    const float* fb1  = (const float*)d_in[9];
    const float* fw2  = (const float*)d_in[10];
    const float* fb2  = (const float*)d_in[11];
    float* out = (float*)d_out;

    const int N = in_sizes[3];                // batch vector length
    const int E = in_sizes[1] / 2;            // edge_index is (2, E)
    const int NCLASS = in_sizes[11];          // fb2 length
    const int G = out_size / NCLASS;

    const int* row = eidx;
    const int* col = eidx + E;

    // ---- workspace layout (8B-aligned arrays first) ----
    char* wp = (char*)d_ws;
    u64*   packed = (u64*)wp;    wp += sizeof(u64) * N;
    u64*   csr    = (u64*)wp;    wp += sizeof(u64) * E;
    float* dinv   = (float*)wp;  wp += sizeof(float) * N;
    __half* hbuf  = (__half*)wp; wp += sizeof(__half) * (size_t)N * HIDC;
    float* bufB   = (float*)wp;  wp += sizeof(float) * (size_t)N * HIDC;
    float* pooled = (float*)wp;  wp += sizeof(float) * (size_t)G * HIDC;
    float* cnt    = (float*)wp;  wp += sizeof(float) * G;
    int*   off    = (int*)wp;    wp += sizeof(int) * (N + 1);
    int*   cursor = (int*)wp;    wp += sizeof(int) * N;
    int*   bsum   = (int*)wp;    wp += sizeof(int) * 256;

    const int BLK = 256;
    dim3 blk(BLK);
    int gN   = (N + BLK - 1) / BLK;
    int gE   = (E + BLK - 1) / BLK;
    int gN64 = ((size_t)N * HIDC + BLK - 1) / BLK;
    int gTile = (N + MTILE - 1) / MTILE;
    int nScanBlocks = (N + SCAN_CHUNK - 1) / SCAN_CHUNK;   // <= 256 for N <= 262144

    // packed degree/count accumulation
    k_init_packed<<<gN, blk, 0, stream>>>(packed, N);
    k_edge_stats<<<gE, blk, 0, stream>>>(col, ew, packed, E);

    // CSR by destination: scan counts (+dinv) -> offsets -> scatter
    k_scan_block<<<nScanBlocks, blk, 0, stream>>>(packed, off, bsum, dinv, N);
    k_scan_sums<<<1, blk, 0, stream>>>(bsum, nScanBlocks);
    k_scan_add<<<gN, blk, 0, stream>>>(off, cursor, bsum, N, E);
    k_scatter_csr<<<gE, blk, 0, stream>>>(row, col, ew, dinv, cursor, csr, E);

    // layer 1: h = fp16(x@W1) ; gather(h)+bias+relu -> B (fp32)
    k_gemm_tile<22><<<gTile, blk, 0, stream>>>(x, W1, hbuf, N);
    k_gcn_gather<<<gN64, blk, 0, stream>>>(hbuf, off, csr, dinv, b1, bufB, N);

    // layer 2: h2 = fp16(B@W2) ; gather(h2)+bias+relu -> B (fp32)
    k_gemm_tile<64><<<gTile, blk, 0, stream>>>(bufB, W2, hbuf, N);
    k_gcn_gather<<<gN64, blk, 0, stream>>>(hbuf, off, csr, dinv, b2, bufB, N);

    // pool (count fused)
    int zeroN = G * HIDC + G;   // pooled + cnt are contiguous
    k_zero<<<(zeroN + BLK - 1) / BLK, blk, 0, stream>>>(pooled, zeroN);
    k_pool<<<(N + 255) / 256, blk, 0, stream>>>(bufB, batch, pooled, cnt, N);

    // head
    k_head<<<G, dim3(64), 0, stream>>>(pooled, cnt, fw1, fb1, fw2, fb2, out, NCLASS);
}

// Round 6
// 287.775 us; speedup vs baseline: 7.7324x; 1.2667x over previous
//
#include <hip/hip_runtime.h>
#include <hip/hip_bf16.h>
#include <hip/hip_fp16.h>

// GCN forward: 2x GCNConv(relu) -> global_mean_pool -> MLP head.
// Round 6: CSR build via bucket partition (LDS-staged, coalesced flushes);
//          degrees via LDS atomics per bucket; dinv folded into GEMM output
//          so CSR weight = raw edge weight. fp16 feature rows for the gather.

#define HIDC 64
#define MTILE 128
#define XS_STRIDE (MTILE + 4)
#define BSHIFT 9
#define SPAN 512          // nodes per bucket
#define NBKT_MAX 256      // requires N <= 131072
#define BCHUNK 2048       // edges per workgroup in k_bin_scatter

typedef unsigned long long u64;

__global__ void k_zero_int(int* p, int n) {
    int i = blockIdx.x * blockDim.x + threadIdx.x;
    if (i < n) p[i] = 0;
}

// per-workgroup LDS histogram of edge destinations by bucket
__global__ __launch_bounds__(256) void k_bin_count(const int* __restrict__ col,
                                                   int* bucket_cnt, int E, int NB) {
    __shared__ int hist[NBKT_MAX];
    int tid = threadIdx.x;
    for (int i = tid; i < NB; i += 256) hist[i] = 0;
    __syncthreads();
    int base = blockIdx.x * 8192;
    for (int j = 0; j < 32; ++j) {
        int e = base + j * 256 + tid;
        if (e < E) atomicAdd(&hist[col[e] >> BSHIFT], 1);
    }
    __syncthreads();
    for (int i = tid; i < NB; i += 256)
        if (hist[i]) atomicAdd(&bucket_cnt[i], hist[i]);
}

// exclusive scan of bucket counts (NB <= 256); emits base + cursor copy
__global__ void k_bucket_scan(const int* __restrict__ bucket_cnt, int* __restrict__ bucket_base,
                              int* __restrict__ cursor_g, int NB, int E) {
    __shared__ int s[256];
    int t = threadIdx.x;
    int v = (t < NB) ? bucket_cnt[t] : 0;
    s[t] = v;
    __syncthreads();
    for (int o = 1; o < 256; o <<= 1) {
        int x = (t >= o) ? s[t - o] : 0;
        __syncthreads();
        s[t] += x;
        __syncthreads();
    }
    if (t < NB) { int ex = s[t] - v; bucket_base[t] = ex; cursor_g[t] = ex; }
    if (t == 0) bucket_base[NB] = E;
}

// partition edges into destination buckets via LDS staging; flushes are
// contiguous runs per bucket (coalesced). packed = ew(32) | src(23) | colin(9).
__global__ __launch_bounds__(256) void k_bin_scatter(const int* __restrict__ row,
                                                     const int* __restrict__ col,
                                                     const float* __restrict__ ew,
                                                     int* cursor_g, u64* __restrict__ bedges,
                                                     int E, int NB) {
    __shared__ int hist[NBKT_MAX], binoff[NBKT_MAX], cursor[NBKT_MAX], gbase[NBKT_MAX];
    __shared__ int s[256];
    __shared__ u64 stage[BCHUNK];
    __shared__ unsigned char binid[BCHUNK];
    int tid = threadIdx.x;
    for (int i = tid; i < NB; i += 256) hist[i] = 0;
    __syncthreads();
    int base = blockIdx.x * BCHUNK;
    u64 pk[8]; int bb[8];
#pragma unroll
    for (int j = 0; j < 8; ++j) {
        int e = base + j * 256 + tid;
        if (e < E) {
            int c = col[e];
            bb[j] = c >> BSHIFT;
            pk[j] = ((u64)__float_as_uint(ew[e]) << 32) |
                    ((u64)(unsigned)row[e] << BSHIFT) | (unsigned)(c & (SPAN - 1));
            atomicAdd(&hist[bb[j]], 1);
        } else bb[j] = -1;
    }
    __syncthreads();
    {   // exclusive scan of hist -> binoff
        int v = (tid < NB) ? hist[tid] : 0;
        s[tid] = v;
        __syncthreads();
        for (int o = 1; o < 256; o <<= 1) {
            int x = (tid >= o) ? s[tid - o] : 0;
            __syncthreads();
            s[tid] += x;
            __syncthreads();
        }
        if (tid < NB) { binoff[tid] = s[tid] - v; cursor[tid] = s[tid] - v; }
    }
    __syncthreads();
#pragma unroll
    for (int j = 0; j < 8; ++j)
        if (bb[j] >= 0) {
            int pos = atomicAdd(&cursor[bb[j]], 1);
            stage[pos] = pk[j];
            binid[pos] = (unsigned char)bb[j];
        }
    __syncthreads();
    if (tid < NB && hist[tid] > 0) gbase[tid] = atomicAdd(&cursor_g[tid], hist[tid]);
    __syncthreads();
    int total = min(BCHUNK, E - base);
    for (int i = tid; i < total; i += 256) {
        int b = binid[i];
        bedges[(size_t)gbase[b] + (i - binoff[b])] = stage[i];
    }
}

// one workgroup per bucket: LDS degree/count accumulate, LDS scan -> CSR offsets,
// in-bucket scatter (L2-resident region), emit dinv + off coalesced.
__global__ __launch_bounds__(256) void k_bucket_process(const u64* __restrict__ bedges,
                                                        const int* __restrict__ bucket_base,
                                                        u64* __restrict__ csr,
                                                        float* __restrict__ dinv,
                                                        int* __restrict__ off,
                                                        int N, int E, int NB) {
    __shared__ float deg[SPAN];
    __shared__ int cL[SPAN];
    __shared__ int offL[SPAN];
    __shared__ int s[256];
    int b = blockIdx.x, tid = threadIdx.x;
    int ebase = bucket_base[b], ecnt = bucket_base[b + 1] - ebase;
    int nd0 = b << BSHIFT;
    int ndn = min(SPAN, N - nd0);
    for (int i = tid; i < SPAN; i += 256) { deg[i] = 1.0f; cL[i] = 0; }
    __syncthreads();
    for (int e = tid; e < ecnt; e += 256) {
        u64 p = bedges[ebase + e];
        int colin = (int)(p & (SPAN - 1));
        atomicAdd(&deg[colin], __uint_as_float((unsigned)(p >> 32)));
        atomicAdd(&cL[colin], 1);
    }
    __syncthreads();
    // exclusive scan of cL[0..SPAN) via pairs (SPAN = 2*256)
    int p0 = cL[2 * tid], p1 = cL[2 * tid + 1];
    s[tid] = p0 + p1;
    __syncthreads();
    for (int o = 1; o < 256; o <<= 1) {
        int x = (tid >= o) ? s[tid - o] : 0;
        __syncthreads();
        s[tid] += x;
        __syncthreads();
    }
    int ex = s[tid] - (p0 + p1);
    offL[2 * tid] = ex;
    offL[2 * tid + 1] = ex + p0;
    __syncthreads();
    for (int i = tid; i < ndn; i += 256) {
        dinv[nd0 + i] = rsqrtf(deg[i]);
        off[nd0 + i] = ebase + offL[i];
    }
    for (int i = tid; i < SPAN; i += 256) cL[i] = offL[i];   // cursors
    if (b == NB - 1 && tid == 0) off[N] = E;
    __syncthreads();
    for (int e = tid; e < ecnt; e += 256) {
        u64 p = bedges[ebase + e];
        int colin = (int)(p & (SPAN - 1));
        int src = (int)((p >> BSHIFT) & 0x7FFFFF);   // 23 bits
        int slot = atomicAdd(&cL[colin], 1);
        csr[(size_t)ebase + slot] = ((u64)(unsigned)src << 32) | (unsigned)(p >> 32);
    }
}

// Tiled GEMM: h'[n][64] = dinv[n] * (x[n][K] @ W[K][64]), output fp16 (RNE).
template <int K>
__global__ __launch_bounds__(256) void k_gemm_tile(const float* __restrict__ x,
                                                   const float* __restrict__ W,
                                                   const float* __restrict__ dinv,
                                                   __half* __restrict__ h, int n) {
    __shared__ float xs[K * XS_STRIDE];   // [K][MTILE] transposed, padded
    __shared__ float ws[K * HIDC];        // [K][64]
    int tid = threadIdx.x;
    int n0 = blockIdx.x * MTILE;

    for (int i = tid; i < K * HIDC; i += 256) ws[i] = W[i];

    if constexpr ((K & 3) == 0) {
        constexpr int KQ = K / 4;
        for (int i = tid; i < MTILE * KQ; i += 256) {
            int r = i / KQ, kq = i - r * KQ;
            float4 v = make_float4(0.f, 0.f, 0.f, 0.f);
            if (n0 + r < n)
                v = *reinterpret_cast<const float4*>(x + (size_t)(n0 + r) * K + kq * 4);
            int k0 = kq * 4;
            xs[(k0 + 0) * XS_STRIDE + r] = v.x;
            xs[(k0 + 1) * XS_STRIDE + r] = v.y;
            xs[(k0 + 2) * XS_STRIDE + r] = v.z;
            xs[(k0 + 3) * XS_STRIDE + r] = v.w;
        }
    } else {
        for (int i = tid; i < MTILE * K; i += 256) {
            int r = i / K, k = i - r * K;
            float v = (n0 + r < n) ? x[(size_t)(n0 + r) * K + k] : 0.f;
            xs[k * XS_STRIDE + r] = v;
        }
    }
    __syncthreads();

    int c0 = (tid & 15) * 4;
    int m0 = (tid >> 4) * 8;
    float acc[8][4];
#pragma unroll
    for (int j = 0; j < 8; ++j)
#pragma unroll
        for (int q = 0; q < 4; ++q) acc[j][q] = 0.f;

#pragma unroll 4
    for (int k = 0; k < K; ++k) {
        float4 a0 = *reinterpret_cast<const float4*>(&xs[k * XS_STRIDE + m0]);
        float4 a1 = *reinterpret_cast<const float4*>(&xs[k * XS_STRIDE + m0 + 4]);
        float4 b  = *reinterpret_cast<const float4*>(&ws[k * HIDC + c0]);
        float av[8] = {a0.x, a0.y, a0.z, a0.w, a1.x, a1.y, a1.z, a1.w};
        float bv[4] = {b.x, b.y, b.z, b.w};
#pragma unroll
        for (int j = 0; j < 8; ++j)
#pragma unroll
            for (int q = 0; q < 4; ++q)
                acc[j][q] = fmaf(av[j], bv[q], acc[j][q]);
    }

#pragma unroll
    for (int j = 0; j < 8; ++j) {
        int node = n0 + m0 + j;
        if (node < n) {
            float dv = dinv[node];
            union { struct { __half2 a, b; } h2; float2 f2; } u;
            u.h2.a = __floats2half2_rn(acc[j][0] * dv, acc[j][1] * dv);
            u.h2.b = __floats2half2_rn(acc[j][2] * dv, acc[j][3] * dv);
            *reinterpret_cast<float2*>(h + (size_t)node * HIDC + c0) = u.f2;
        }
    }
}

// One wave per node: out = dinv[c]*(h'[c] + sum_e ew_e*h'[src_e]) + b, relu.
__global__ void k_gcn_gather(const __half* __restrict__ h, const int* __restrict__ off,
                             const u64* __restrict__ csr, const float* __restrict__ dinv,
                             const float* __restrict__ bias, float* __restrict__ out, int n) {
    int node = (blockIdx.x * blockDim.x + threadIdx.x) >> 6;
    int lane = threadIdx.x & 63;
    if (node >= n) return;
    float d = dinv[node];
    float acc = __half2float(h[(size_t)node * HIDC + lane]);
    int i = off[node], s1 = off[node + 1];
    for (; i + 1 < s1; i += 2) {
        u64 eA = csr[i], eB = csr[i + 1];
        int sA = (int)(eA >> 32), sB = (int)(eB >> 32);
        float wA = __uint_as_float((unsigned)eA);
        float wB = __uint_as_float((unsigned)eB);
        float hA = __half2float(h[(size_t)sA * HIDC + lane]);
        float hB = __half2float(h[(size_t)sB * HIDC + lane]);
        acc = fmaf(wA, hA, acc);
        acc = fmaf(wB, hB, acc);
    }
    if (i < s1) {
        u64 eA = csr[i];
        acc = fmaf(__uint_as_float((unsigned)eA),
                   __half2float(h[(size_t)(eA >> 32) * HIDC + lane]), acc);
    }
    out[(size_t)node * HIDC + lane] = fmaxf(fmaf(d, acc, bias[lane]), 0.f);
}

__global__ void k_zero(float* p, int n) {
    int i = blockIdx.x * blockDim.x + threadIdx.x;
    if (i < n) p[i] = 0.f;
}

// batch is sorted: segmented accumulate, flush (atomic) only on graph change.
__global__ void k_pool(const float* __restrict__ h, const int* __restrict__ batch,
                       float* __restrict__ pooled, float* __restrict__ cnt, int n) {
    int c = threadIdx.x & 63, sub = threadIdx.x >> 6;
    int n0 = blockIdx.x * 256;
    int nend = min(n0 + 256, n);
    float acc = 0.f, cacc = 0.f;
    int curb = -1;
    for (int i = n0 + sub; i < nend; i += 4) {
        int b = batch[i];
        if (b != curb) {
            if (curb >= 0) {
                atomicAdd(&pooled[curb * HIDC + c], acc);
                if (c == 0) atomicAdd(&cnt[curb], cacc);
            }
            acc = 0.f; cacc = 0.f;
            curb = b;
        }
        acc += h[(size_t)i * HIDC + c];
        cacc += 1.f;
    }
    if (curb >= 0) {
        atomicAdd(&pooled[curb * HIDC + c], acc);
        if (c == 0) atomicAdd(&cnt[curb], cacc);
    }
}

// One 64-thread block per graph: mean, fc1+relu, fc2.
__global__ void k_head(const float* __restrict__ pooled, const float* __restrict__ cnt,
                       const float* __restrict__ fw1, const float* __restrict__ fb1,
                       const float* __restrict__ fw2, const float* __restrict__ fb2,
                       float* __restrict__ out, int nclass) {
    int g = blockIdx.x;
    int j = threadIdx.x;
    __shared__ float p[HIDC], hid[HIDC];
    float c = fmaxf(cnt[g], 1.0f);
    p[j] = pooled[g * HIDC + j] / c;
    __syncthreads();
    float acc = fb1[j];
#pragma unroll 8
    for (int k = 0; k < HIDC; ++k) acc = fmaf(p[k], fw1[k * HIDC + j], acc);
    hid[j] = fmaxf(acc, 0.f);
    __syncthreads();
    if (j < nclass) {
        float o = fb2[j];
#pragma unroll 8
        for (int k = 0; k < HIDC; ++k) o = fmaf(hid[k], fw2[k * nclass + j], o);
        out[g * nclass + j] = o;
    }
}

extern "C" void kernel_launch(void* const* d_in, const int* in_sizes, int n_in,
                              void* d_out, int out_size, void* d_ws, size_t ws_size,
                              hipStream_t stream) {
    const float* x    = (const float*)d_in[0];
    const int* eidx   = (const int*)d_in[1];
    const float* ew   = (const float*)d_in[2];
    const int* batch  = (const int*)d_in[3];
    const float* W1   = (const float*)d_in[4];
    const float* b1   = (const float*)d_in[5];
    const float* W2   = (const float*)d_in[6];
    const float* b2   = (const float*)d_in[7];
    const float* fw1  = (const float*)d_in[8];
    const float* fb1  = (const float*)d_in[9];
    const float* fw2  = (const float*)d_in[10];
    const float* fb2  = (const float*)d_in[11];
    float* out = (float*)d_out;

    const int N = in_sizes[3];
    const int E = in_sizes[1] / 2;
    const int NCLASS = in_sizes[11];
    const int G = out_size / NCLASS;
    const int NB = (N + SPAN - 1) >> BSHIFT;   // 196 for N=100000 (<=256 req.)

    const int* row = eidx;
    const int* col = eidx + E;

    // ---- workspace layout (8B-aligned arrays first) ----
    char* wp = (char*)d_ws;
    u64*   bedges = (u64*)wp;    wp += sizeof(u64) * E;
    u64*   csr    = (u64*)wp;    wp += sizeof(u64) * E;
    float* dinv   = (float*)wp;  wp += sizeof(float) * N;
    __half* hbuf  = (__half*)wp; wp += sizeof(__half) * (size_t)N * HIDC;
    float* bufB   = (float*)wp;  wp += sizeof(float) * (size_t)N * HIDC;
    float* pooled = (float*)wp;  wp += sizeof(float) * (size_t)G * HIDC;
    float* cnt    = (float*)wp;  wp += sizeof(float) * G;
    int*   off    = (int*)wp;    wp += sizeof(int) * (N + 1);
    int*   bucket_cnt  = (int*)wp; wp += sizeof(int) * NBKT_MAX;
    int*   bucket_base = (int*)wp; wp += sizeof(int) * (NBKT_MAX + 1);
    int*   cursor_g    = (int*)wp; wp += sizeof(int) * NBKT_MAX;

    const int BLK = 256;
    dim3 blk(BLK);
    int gN64 = ((size_t)N * HIDC + BLK - 1) / BLK;
    int gTile = (N + MTILE - 1) / MTILE;

    // CSR build via bucket partition
    k_zero_int<<<1, blk, 0, stream>>>(bucket_cnt, NB);
    k_bin_count<<<(E + 8191) / 8192, blk, 0, stream>>>(col, bucket_cnt, E, NB);
    k_bucket_scan<<<1, blk, 0, stream>>>(bucket_cnt, bucket_base, cursor_g, NB, E);
    k_bin_scatter<<<(E + BCHUNK - 1) / BCHUNK, blk, 0, stream>>>(row, col, ew, cursor_g,
                                                                 bedges, E, NB);
    k_bucket_process<<<NB, blk, 0, stream>>>(bedges, bucket_base, csr, dinv, off, N, E, NB);

    // layer 1: h' = fp16(dinv * (x@W1)) ; gather+bias+relu -> B (fp32)
    k_gemm_tile<22><<<gTile, blk, 0, stream>>>(x, W1, dinv, hbuf, N);
    k_gcn_gather<<<gN64, blk, 0, stream>>>(hbuf, off, csr, dinv, b1, bufB, N);

    // layer 2
    k_gemm_tile<64><<<gTile, blk, 0, stream>>>(bufB, W2, dinv, hbuf, N);
    k_gcn_gather<<<gN64, blk, 0, stream>>>(hbuf, off, csr, dinv, b2, bufB, N);

    // pool (count fused)
    int zeroN = G * HIDC + G;
    k_zero<<<(zeroN + BLK - 1) / BLK, blk, 0, stream>>>(pooled, zeroN);
    k_pool<<<(N + 255) / 256, blk, 0, stream>>>(bufB, batch, pooled, cnt, N);

    // head
    k_head<<<G, dim3(64), 0, stream>>>(pooled, cnt, fw1, fb1, fw2, fb2, out, NCLASS);
}

// Round 7
// 215.673 us; speedup vs baseline: 10.3175x; 1.3343x over previous
//
#include <hip/hip_runtime.h>
#include <hip/hip_bf16.h>
#include <hip/hip_fp16.h>

// GCN forward: 2x GCNConv(relu) -> global_mean_pool -> MLP head.
// Round 7: gather rewritten for memory-level parallelism — 2 nodes/wave
//          (half-wave each, half2 loads) + 4-wide edge unroll = 8 row
//          fetches in flight per wave (was 2).

#define HIDC 64
#define MTILE 128
#define XS_STRIDE (MTILE + 4)
#define BSHIFT 9
#define SPAN 512          // nodes per bucket
#define NBKT_MAX 256      // requires N <= 131072
#define BCHUNK 2048       // edges per workgroup in k_bin_scatter

typedef unsigned long long u64;

__global__ void k_zero_int(int* p, int n) {
    int i = blockIdx.x * blockDim.x + threadIdx.x;
    if (i < n) p[i] = 0;
}

// per-workgroup LDS histogram of edge destinations by bucket
__global__ __launch_bounds__(256) void k_bin_count(const int* __restrict__ col,
                                                   int* bucket_cnt, int E, int NB) {
    __shared__ int hist[NBKT_MAX];
    int tid = threadIdx.x;
    for (int i = tid; i < NB; i += 256) hist[i] = 0;
    __syncthreads();
    int base = blockIdx.x * 8192;
    for (int j = 0; j < 32; ++j) {
        int e = base + j * 256 + tid;
        if (e < E) atomicAdd(&hist[col[e] >> BSHIFT], 1);
    }
    __syncthreads();
    for (int i = tid; i < NB; i += 256)
        if (hist[i]) atomicAdd(&bucket_cnt[i], hist[i]);
}

// exclusive scan of bucket counts (NB <= 256); emits base + cursor copy
__global__ void k_bucket_scan(const int* __restrict__ bucket_cnt, int* __restrict__ bucket_base,
                              int* __restrict__ cursor_g, int NB, int E) {
    __shared__ int s[256];
    int t = threadIdx.x;
    int v = (t < NB) ? bucket_cnt[t] : 0;
    s[t] = v;
    __syncthreads();
    for (int o = 1; o < 256; o <<= 1) {
        int x = (t >= o) ? s[t - o] : 0;
        __syncthreads();
        s[t] += x;
        __syncthreads();
    }
    if (t < NB) { int ex = s[t] - v; bucket_base[t] = ex; cursor_g[t] = ex; }
    if (t == 0) bucket_base[NB] = E;
}

// partition edges into destination buckets via LDS staging; flushes are
// contiguous runs per bucket (coalesced). packed = ew(32) | src(23) | colin(9).
__global__ __launch_bounds__(256) void k_bin_scatter(const int* __restrict__ row,
                                                     const int* __restrict__ col,
                                                     const float* __restrict__ ew,
                                                     int* cursor_g, u64* __restrict__ bedges,
                                                     int E, int NB) {
    __shared__ int hist[NBKT_MAX], binoff[NBKT_MAX], cursor[NBKT_MAX], gbase[NBKT_MAX];
    __shared__ int s[256];
    __shared__ u64 stage[BCHUNK];
    __shared__ unsigned char binid[BCHUNK];
    int tid = threadIdx.x;
    for (int i = tid; i < NB; i += 256) hist[i] = 0;
    __syncthreads();
    int base = blockIdx.x * BCHUNK;
    u64 pk[8]; int bb[8];
#pragma unroll
    for (int j = 0; j < 8; ++j) {
        int e = base + j * 256 + tid;
        if (e < E) {
            int c = col[e];
            bb[j] = c >> BSHIFT;
            pk[j] = ((u64)__float_as_uint(ew[e]) << 32) |
                    ((u64)(unsigned)row[e] << BSHIFT) | (unsigned)(c & (SPAN - 1));
            atomicAdd(&hist[bb[j]], 1);
        } else bb[j] = -1;
    }
    __syncthreads();
    {   // exclusive scan of hist -> binoff
        int v = (tid < NB) ? hist[tid] : 0;
        s[tid] = v;
        __syncthreads();
        for (int o = 1; o < 256; o <<= 1) {
            int x = (tid >= o) ? s[tid - o] : 0;
            __syncthreads();
            s[tid] += x;
            __syncthreads();
        }
        if (tid < NB) { binoff[tid] = s[tid] - v; cursor[tid] = s[tid] - v; }
    }
    __syncthreads();
#pragma unroll
    for (int j = 0; j < 8; ++j)
        if (bb[j] >= 0) {
            int pos = atomicAdd(&cursor[bb[j]], 1);
            stage[pos] = pk[j];
            binid[pos] = (unsigned char)bb[j];
        }
    __syncthreads();
    if (tid < NB && hist[tid] > 0) gbase[tid] = atomicAdd(&cursor_g[tid], hist[tid]);
    __syncthreads();
    int total = min(BCHUNK, E - base);
    for (int i = tid; i < total; i += 256) {
        int b = binid[i];
        bedges[(size_t)gbase[b] + (i - binoff[b])] = stage[i];
    }
}

// one workgroup per bucket: LDS degree/count accumulate, LDS scan -> CSR offsets,
// in-bucket scatter (L2-resident region), emit dinv + off coalesced.
__global__ __launch_bounds__(256) void k_bucket_process(const u64* __restrict__ bedges,
                                                        const int* __restrict__ bucket_base,
                                                        u64* __restrict__ csr,
                                                        float* __restrict__ dinv,
                                                        int* __restrict__ off,
                                                        int N, int E, int NB) {
    __shared__ float deg[SPAN];
    __shared__ int cL[SPAN];
    __shared__ int offL[SPAN];
    __shared__ int s[256];
    int b = blockIdx.x, tid = threadIdx.x;
    int ebase = bucket_base[b], ecnt = bucket_base[b + 1] - ebase;
    int nd0 = b << BSHIFT;
    int ndn = min(SPAN, N - nd0);
    for (int i = tid; i < SPAN; i += 256) { deg[i] = 1.0f; cL[i] = 0; }
    __syncthreads();
    for (int e = tid; e < ecnt; e += 256) {
        u64 p = bedges[ebase + e];
        int colin = (int)(p & (SPAN - 1));
        atomicAdd(&deg[colin], __uint_as_float((unsigned)(p >> 32)));
        atomicAdd(&cL[colin], 1);
    }
    __syncthreads();
    // exclusive scan of cL[0..SPAN) via pairs (SPAN = 2*256)
    int p0 = cL[2 * tid], p1 = cL[2 * tid + 1];
    s[tid] = p0 + p1;
    __syncthreads();
    for (int o = 1; o < 256; o <<= 1) {
        int x = (tid >= o) ? s[tid - o] : 0;
        __syncthreads();
        s[tid] += x;
        __syncthreads();
    }
    int ex = s[tid] - (p0 + p1);
    offL[2 * tid] = ex;
    offL[2 * tid + 1] = ex + p0;
    __syncthreads();
    for (int i = tid; i < ndn; i += 256) {
        dinv[nd0 + i] = rsqrtf(deg[i]);
        off[nd0 + i] = ebase + offL[i];
    }
    for (int i = tid; i < SPAN; i += 256) cL[i] = offL[i];   // cursors
    if (b == NB - 1 && tid == 0) off[N] = E;
    __syncthreads();
    for (int e = tid; e < ecnt; e += 256) {
        u64 p = bedges[ebase + e];
        int colin = (int)(p & (SPAN - 1));
        int src = (int)((p >> BSHIFT) & 0x7FFFFF);   // 23 bits
        int slot = atomicAdd(&cL[colin], 1);
        csr[(size_t)ebase + slot] = ((u64)(unsigned)src << 32) | (unsigned)(p >> 32);
    }
}

// Tiled GEMM: h'[n][64] = dinv[n] * (x[n][K] @ W[K][64]), output fp16 (RNE).
template <int K>
__global__ __launch_bounds__(256) void k_gemm_tile(const float* __restrict__ x,
                                                   const float* __restrict__ W,
                                                   const float* __restrict__ dinv,
                                                   __half* __restrict__ h, int n) {
    __shared__ float xs[K * XS_STRIDE];   // [K][MTILE] transposed, padded
    __shared__ float ws[K * HIDC];        // [K][64]
    int tid = threadIdx.x;
    int n0 = blockIdx.x * MTILE;

    for (int i = tid; i < K * HIDC; i += 256) ws[i] = W[i];

    if constexpr ((K & 3) == 0) {
        constexpr int KQ = K / 4;
        for (int i = tid; i < MTILE * KQ; i += 256) {
            int r = i / KQ, kq = i - r * KQ;
            float4 v = make_float4(0.f, 0.f, 0.f, 0.f);
            if (n0 + r < n)
                v = *reinterpret_cast<const float4*>(x + (size_t)(n0 + r) * K + kq * 4);
            int k0 = kq * 4;
            xs[(k0 + 0) * XS_STRIDE + r] = v.x;
            xs[(k0 + 1) * XS_STRIDE + r] = v.y;
            xs[(k0 + 2) * XS_STRIDE + r] = v.z;
            xs[(k0 + 3) * XS_STRIDE + r] = v.w;
        }
    } else {
        for (int i = tid; i < MTILE * K; i += 256) {
            int r = i / K, k = i - r * K;
            float v = (n0 + r < n) ? x[(size_t)(n0 + r) * K + k] : 0.f;
            xs[k * XS_STRIDE + r] = v;
        }
    }
    __syncthreads();

    int c0 = (tid & 15) * 4;
    int m0 = (tid >> 4) * 8;
    float acc[8][4];
#pragma unroll
    for (int j = 0; j < 8; ++j)
#pragma unroll
        for (int q = 0; q < 4; ++q) acc[j][q] = 0.f;

#pragma unroll 4
    for (int k = 0; k < K; ++k) {
        float4 a0 = *reinterpret_cast<const float4*>(&xs[k * XS_STRIDE + m0]);
        float4 a1 = *reinterpret_cast<const float4*>(&xs[k * XS_STRIDE + m0 + 4]);
        float4 b  = *reinterpret_cast<const float4*>(&ws[k * HIDC + c0]);
        float av[8] = {a0.x, a0.y, a0.z, a0.w, a1.x, a1.y, a1.z, a1.w};
        float bv[4] = {b.x, b.y, b.z, b.w};
#pragma unroll
        for (int j = 0; j < 8; ++j)
#pragma unroll
            for (int q = 0; q < 4; ++q)
                acc[j][q] = fmaf(av[j], bv[q], acc[j][q]);
    }

#pragma unroll
    for (int j = 0; j < 8; ++j) {
        int node = n0 + m0 + j;
        if (node < n) {
            float dv = dinv[node];
            union { struct { __half2 a, b; } h2; float2 f2; } u;
            u.h2.a = __floats2half2_rn(acc[j][0] * dv, acc[j][1] * dv);
            u.h2.b = __floats2half2_rn(acc[j][2] * dv, acc[j][3] * dv);
            *reinterpret_cast<float2*>(h + (size_t)node * HIDC + c0) = u.f2;
        }
    }
}

// Gather: 2 nodes per wave (half-wave each), half2 channel pairs, 4-wide edge
// unroll -> 8 independent row fetches in flight per wave.
// out = dinv[c]*(h'[c] + sum_e ew_e*h'[src_e]) + b, relu.
__global__ void k_gcn_gather(const __half* __restrict__ h, const int* __restrict__ off,
                             const u64* __restrict__ csr, const float* __restrict__ dinv,
                             const float* __restrict__ bias, float* __restrict__ out, int n) {
    int t = blockIdx.x * blockDim.x + threadIdx.x;
    int lane = threadIdx.x & 63;
    int node = ((t >> 6) << 1) + (lane >> 5);   // 2 nodes per wave
    int sub = lane & 31;                        // half2 index (channels 2*sub, 2*sub+1)
    if (node >= n) return;
    const __half2* hp = reinterpret_cast<const __half2*>(h);
    float d = dinv[node];
    float2 sv = __half22float2(hp[(size_t)node * 32 + sub]);
    float acc0 = sv.x, acc1 = sv.y;
    int i = off[node], e1 = off[node + 1];
    for (; i + 3 < e1; i += 4) {
        u64 eA = csr[i], eB = csr[i + 1], eC = csr[i + 2], eD = csr[i + 3];
        float2 hA = __half22float2(hp[(size_t)(eA >> 32) * 32 + sub]);
        float2 hB = __half22float2(hp[(size_t)(eB >> 32) * 32 + sub]);
        float2 hC = __half22float2(hp[(size_t)(eC >> 32) * 32 + sub]);
        float2 hD = __half22float2(hp[(size_t)(eD >> 32) * 32 + sub]);
        float wA = __uint_as_float((unsigned)eA);
        float wB = __uint_as_float((unsigned)eB);
        float wC = __uint_as_float((unsigned)eC);
        float wD = __uint_as_float((unsigned)eD);
        acc0 = fmaf(wA, hA.x, acc0); acc1 = fmaf(wA, hA.y, acc1);
        acc0 = fmaf(wB, hB.x, acc0); acc1 = fmaf(wB, hB.y, acc1);
        acc0 = fmaf(wC, hC.x, acc0); acc1 = fmaf(wC, hC.y, acc1);
        acc0 = fmaf(wD, hD.x, acc0); acc1 = fmaf(wD, hD.y, acc1);
    }
    for (; i < e1; ++i) {
        u64 eA = csr[i];
        float2 hA = __half22float2(hp[(size_t)(eA >> 32) * 32 + sub]);
        float wA = __uint_as_float((unsigned)eA);
        acc0 = fmaf(wA, hA.x, acc0); acc1 = fmaf(wA, hA.y, acc1);
    }
    int c0 = sub * 2;
    float2 o;
    o.x = fmaxf(fmaf(d, acc0, bias[c0]), 0.f);
    o.y = fmaxf(fmaf(d, acc1, bias[c0 + 1]), 0.f);
    *reinterpret_cast<float2*>(out + (size_t)node * HIDC + c0) = o;
}

__global__ void k_zero(float* p, int n) {
    int i = blockIdx.x * blockDim.x + threadIdx.x;
    if (i < n) p[i] = 0.f;
}

// batch is sorted: segmented accumulate, flush (atomic) only on graph change.
__global__ void k_pool(const float* __restrict__ h, const int* __restrict__ batch,
                       float* __restrict__ pooled, float* __restrict__ cnt, int n) {
    int c = threadIdx.x & 63, sub = threadIdx.x >> 6;
    int n0 = blockIdx.x * 256;
    int nend = min(n0 + 256, n);
    float acc = 0.f, cacc = 0.f;
    int curb = -1;
    for (int i = n0 + sub; i < nend; i += 4) {
        int b = batch[i];
        if (b != curb) {
            if (curb >= 0) {
                atomicAdd(&pooled[curb * HIDC + c], acc);
                if (c == 0) atomicAdd(&cnt[curb], cacc);
            }
            acc = 0.f; cacc = 0.f;
            curb = b;
        }
        acc += h[(size_t)i * HIDC + c];
        cacc += 1.f;
    }
    if (curb >= 0) {
        atomicAdd(&pooled[curb * HIDC + c], acc);
        if (c == 0) atomicAdd(&cnt[curb], cacc);
    }
}

// One 64-thread block per graph: mean, fc1+relu, fc2.
__global__ void k_head(const float* __restrict__ pooled, const float* __restrict__ cnt,
                       const float* __restrict__ fw1, const float* __restrict__ fb1,
                       const float* __restrict__ fw2, const float* __restrict__ fb2,
                       float* __restrict__ out, int nclass) {
    int g = blockIdx.x;
    int j = threadIdx.x;
    __shared__ float p[HIDC], hid[HIDC];
    float c = fmaxf(cnt[g], 1.0f);
    p[j] = pooled[g * HIDC + j] / c;
    __syncthreads();
    float acc = fb1[j];
#pragma unroll 8
    for (int k = 0; k < HIDC; ++k) acc = fmaf(p[k], fw1[k * HIDC + j], acc);
    hid[j] = fmaxf(acc, 0.f);
    __syncthreads();
    if (j < nclass) {
        float o = fb2[j];
#pragma unroll 8
        for (int k = 0; k < HIDC; ++k) o = fmaf(hid[k], fw2[k * nclass + j], o);
        out[g * nclass + j] = o;
    }
}

extern "C" void kernel_launch(void* const* d_in, const int* in_sizes, int n_in,
                              void* d_out, int out_size, void* d_ws, size_t ws_size,
                              hipStream_t stream) {
    const float* x    = (const float*)d_in[0];
    const int* eidx   = (const int*)d_in[1];
    const float* ew   = (const float*)d_in[2];
    const int* batch  = (const int*)d_in[3];
    const float* W1   = (const float*)d_in[4];
    const float* b1   = (const float*)d_in[5];
    const float* W2   = (const float*)d_in[6];
    const float* b2   = (const float*)d_in[7];
    const float* fw1  = (const float*)d_in[8];
    const float* fb1  = (const float*)d_in[9];
    const float* fw2  = (const float*)d_in[10];
    const float* fb2  = (const float*)d_in[11];
    float* out = (float*)d_out;

    const int N = in_sizes[3];
    const int E = in_sizes[1] / 2;
    const int NCLASS = in_sizes[11];
    const int G = out_size / NCLASS;
    const int NB = (N + SPAN - 1) >> BSHIFT;   // 196 for N=100000 (<=256 req.)

    const int* row = eidx;
    const int* col = eidx + E;

    // ---- workspace layout (8B-aligned arrays first) ----
    char* wp = (char*)d_ws;
    u64*   bedges = (u64*)wp;    wp += sizeof(u64) * E;
    u64*   csr    = (u64*)wp;    wp += sizeof(u64) * E;
    float* dinv   = (float*)wp;  wp += sizeof(float) * N;
    __half* hbuf  = (__half*)wp; wp += sizeof(__half) * (size_t)N * HIDC;
    float* bufB   = (float*)wp;  wp += sizeof(float) * (size_t)N * HIDC;
    float* pooled = (float*)wp;  wp += sizeof(float) * (size_t)G * HIDC;
    float* cnt    = (float*)wp;  wp += sizeof(float) * G;
    int*   off    = (int*)wp;    wp += sizeof(int) * (N + 1);
    int*   bucket_cnt  = (int*)wp; wp += sizeof(int) * NBKT_MAX;
    int*   bucket_base = (int*)wp; wp += sizeof(int) * (NBKT_MAX + 1);
    int*   cursor_g    = (int*)wp; wp += sizeof(int) * NBKT_MAX;

    const int BLK = 256;
    dim3 blk(BLK);
    int gTile = (N + MTILE - 1) / MTILE;
    // gather: 2 nodes per wave, 4 waves per block -> 8 nodes per block
    int gGather = (N + 7) / 8;

    // CSR build via bucket partition
    k_zero_int<<<1, blk, 0, stream>>>(bucket_cnt, NB);
    k_bin_count<<<(E + 8191) / 8192, blk, 0, stream>>>(col, bucket_cnt, E, NB);
    k_bucket_scan<<<1, blk, 0, stream>>>(bucket_cnt, bucket_base, cursor_g, NB, E);
    k_bin_scatter<<<(E + BCHUNK - 1) / BCHUNK, blk, 0, stream>>>(row, col, ew, cursor_g,
                                                                 bedges, E, NB);
    k_bucket_process<<<NB, blk, 0, stream>>>(bedges, bucket_base, csr, dinv, off, N, E, NB);

    // layer 1: h' = fp16(dinv * (x@W1)) ; gather+bias+relu -> B (fp32)
    k_gemm_tile<22><<<gTile, blk, 0, stream>>>(x, W1, dinv, hbuf, N);
    k_gcn_gather<<<gGather, blk, 0, stream>>>(hbuf, off, csr, dinv, b1, bufB, N);

    // layer 2
    k_gemm_tile<64><<<gTile, blk, 0, stream>>>(bufB, W2, dinv, hbuf, N);
    k_gcn_gather<<<gGather, blk, 0, stream>>>(hbuf, off, csr, dinv, b2, bufB, N);

    // pool (count fused)
    int zeroN = G * HIDC + G;
    k_zero<<<(zeroN + BLK - 1) / BLK, blk, 0, stream>>>(pooled, zeroN);
    k_pool<<<(N + 255) / 256, blk, 0, stream>>>(bufB, batch, pooled, cnt, N);

    // head
    k_head<<<G, dim3(64), 0, stream>>>(pooled, cnt, fw1, fb1, fw2, fb2, out, NCLASS);
}

// Round 8
// 203.059 us; speedup vs baseline: 10.9584x; 1.0621x over previous
//
#include <hip/hip_runtime.h>
#include <hip/hip_bf16.h>
#include <hip/hip_fp16.h>

// GCN forward: 2x GCNConv(relu) -> global_mean_pool -> MLP head.
// Round 8: layer 1 restructured as aggregate-then-transform (gathers 64B
//          padded fp16 x-rows instead of 128B h-rows); 16 fetches in flight
//          per wave in both gathers; bias+relu fused into layer-1 GEMM.

#define HIDC 64
#define MTILE 128
#define XS_STRIDE (MTILE + 4)
#define BSHIFT 9
#define SPAN 512          // nodes per bucket
#define NBKT_MAX 256      // requires N <= 131072
#define BCHUNK 2048       // edges per workgroup in k_bin_scatter

typedef unsigned long long u64;

__global__ void k_zero_int(int* p, int n) {
    int i = blockIdx.x * blockDim.x + threadIdx.x;
    if (i < n) p[i] = 0;
}

// per-workgroup LDS histogram of edge destinations by bucket
__global__ __launch_bounds__(256) void k_bin_count(const int* __restrict__ col,
                                                   int* bucket_cnt, int E, int NB) {
    __shared__ int hist[NBKT_MAX];
    int tid = threadIdx.x;
    for (int i = tid; i < NB; i += 256) hist[i] = 0;
    __syncthreads();
    int base = blockIdx.x * 8192;
    for (int j = 0; j < 32; ++j) {
        int e = base + j * 256 + tid;
        if (e < E) atomicAdd(&hist[col[e] >> BSHIFT], 1);
    }
    __syncthreads();
    for (int i = tid; i < NB; i += 256)
        if (hist[i]) atomicAdd(&bucket_cnt[i], hist[i]);
}

// exclusive scan of bucket counts (NB <= 256); emits base + cursor copy
__global__ void k_bucket_scan(const int* __restrict__ bucket_cnt, int* __restrict__ bucket_base,
                              int* __restrict__ cursor_g, int NB, int E) {
    __shared__ int s[256];
    int t = threadIdx.x;
    int v = (t < NB) ? bucket_cnt[t] : 0;
    s[t] = v;
    __syncthreads();
    for (int o = 1; o < 256; o <<= 1) {
        int x = (t >= o) ? s[t - o] : 0;
        __syncthreads();
        s[t] += x;
        __syncthreads();
    }
    if (t < NB) { int ex = s[t] - v; bucket_base[t] = ex; cursor_g[t] = ex; }
    if (t == 0) bucket_base[NB] = E;
}

// partition edges into destination buckets via LDS staging; flushes are
// contiguous runs per bucket (coalesced). packed = ew(32) | src(23) | colin(9).
__global__ __launch_bounds__(256) void k_bin_scatter(const int* __restrict__ row,
                                                     const int* __restrict__ col,
                                                     const float* __restrict__ ew,
                                                     int* cursor_g, u64* __restrict__ bedges,
                                                     int E, int NB) {
    __shared__ int hist[NBKT_MAX], binoff[NBKT_MAX], cursor[NBKT_MAX], gbase[NBKT_MAX];
    __shared__ int s[256];
    __shared__ u64 stage[BCHUNK];
    __shared__ unsigned char binid[BCHUNK];
    int tid = threadIdx.x;
    for (int i = tid; i < NB; i += 256) hist[i] = 0;
    __syncthreads();
    int base = blockIdx.x * BCHUNK;
    u64 pk[8]; int bb[8];
#pragma unroll
    for (int j = 0; j < 8; ++j) {
        int e = base + j * 256 + tid;
        if (e < E) {
            int c = col[e];
            bb[j] = c >> BSHIFT;
            pk[j] = ((u64)__float_as_uint(ew[e]) << 32) |
                    ((u64)(unsigned)row[e] << BSHIFT) | (unsigned)(c & (SPAN - 1));
            atomicAdd(&hist[bb[j]], 1);
        } else bb[j] = -1;
    }
    __syncthreads();
    {   // exclusive scan of hist -> binoff
        int v = (tid < NB) ? hist[tid] : 0;
        s[tid] = v;
        __syncthreads();
        for (int o = 1; o < 256; o <<= 1) {
            int x = (tid >= o) ? s[tid - o] : 0;
            __syncthreads();
            s[tid] += x;
            __syncthreads();
        }
        if (tid < NB) { binoff[tid] = s[tid] - v; cursor[tid] = s[tid] - v; }
    }
    __syncthreads();
#pragma unroll
    for (int j = 0; j < 8; ++j)
        if (bb[j] >= 0) {
            int pos = atomicAdd(&cursor[bb[j]], 1);
            stage[pos] = pk[j];
            binid[pos] = (unsigned char)bb[j];
        }
    __syncthreads();
    if (tid < NB && hist[tid] > 0) gbase[tid] = atomicAdd(&cursor_g[tid], hist[tid]);
    __syncthreads();
    int total = min(BCHUNK, E - base);
    for (int i = tid; i < total; i += 256) {
        int b = binid[i];
        bedges[(size_t)gbase[b] + (i - binoff[b])] = stage[i];
    }
}

// one workgroup per bucket: LDS degree/count accumulate, LDS scan -> CSR offsets,
// in-bucket scatter (L2-resident region), emit dinv + off coalesced.
__global__ __launch_bounds__(256) void k_bucket_process(const u64* __restrict__ bedges,
                                                        const int* __restrict__ bucket_base,
                                                        u64* __restrict__ csr,
                                                        float* __restrict__ dinv,
                                                        int* __restrict__ off,
                                                        int N, int E, int NB) {
    __shared__ float deg[SPAN];
    __shared__ int cL[SPAN];
    __shared__ int offL[SPAN];
    __shared__ int s[256];
    int b = blockIdx.x, tid = threadIdx.x;
    int ebase = bucket_base[b], ecnt = bucket_base[b + 1] - ebase;
    int nd0 = b << BSHIFT;
    int ndn = min(SPAN, N - nd0);
    for (int i = tid; i < SPAN; i += 256) { deg[i] = 1.0f; cL[i] = 0; }
    __syncthreads();
    for (int e = tid; e < ecnt; e += 256) {
        u64 p = bedges[ebase + e];
        int colin = (int)(p & (SPAN - 1));
        atomicAdd(&deg[colin], __uint_as_float((unsigned)(p >> 32)));
        atomicAdd(&cL[colin], 1);
    }
    __syncthreads();
    // exclusive scan of cL[0..SPAN) via pairs (SPAN = 2*256)
    int p0 = cL[2 * tid], p1 = cL[2 * tid + 1];
    s[tid] = p0 + p1;
    __syncthreads();
    for (int o = 1; o < 256; o <<= 1) {
        int x = (tid >= o) ? s[tid - o] : 0;
        __syncthreads();
        s[tid] += x;
        __syncthreads();
    }
    int ex = s[tid] - (p0 + p1);
    offL[2 * tid] = ex;
    offL[2 * tid + 1] = ex + p0;
    __syncthreads();
    for (int i = tid; i < ndn; i += 256) {
        dinv[nd0 + i] = rsqrtf(deg[i]);
        off[nd0 + i] = ebase + offL[i];
    }
    for (int i = tid; i < SPAN; i += 256) cL[i] = offL[i];   // cursors
    if (b == NB - 1 && tid == 0) off[N] = E;
    __syncthreads();
    for (int e = tid; e < ecnt; e += 256) {
        u64 p = bedges[ebase + e];
        int colin = (int)(p & (SPAN - 1));
        int src = (int)((p >> BSHIFT) & 0x7FFFFF);   // 23 bits
        int slot = atomicAdd(&cL[colin], 1);
        csr[(size_t)ebase + slot] = ((u64)(unsigned)src << 32) | (unsigned)(p >> 32);
    }
}

// x16[n][32] = fp16(dinv[n] * x[n][0..21]), channels 22..31 zero (64B rows).
__global__ void k_prep_x16(const float* __restrict__ x, const float* __restrict__ dinv,
                           __half* __restrict__ x16, int n, int K) {
    int t = blockIdx.x * blockDim.x + threadIdx.x;
    int node = t >> 4, p = t & 15;     // 16 half2 per row
    if (node >= n) return;
    int c0 = p * 2;
    float d = dinv[node];
    float a = (c0 < K)     ? d * x[(size_t)node * K + c0]     : 0.f;
    float b = (c0 + 1 < K) ? d * x[(size_t)node * K + c0 + 1] : 0.f;
    reinterpret_cast<__half2*>(x16)[(size_t)node * 16 + p] = __floats2half2_rn(a, b);
}

// Layer-1 aggregation over raw x: 4 nodes/wave (16 lanes each, one half2/lane),
// 4-wide edge unroll -> 16 row fetches in flight. agg = dinv*(x'+sum w*x'[src]).
__global__ void k_agg_x(const __half* __restrict__ x16, const int* __restrict__ off,
                        const u64* __restrict__ csr, const float* __restrict__ dinv,
                        float* __restrict__ agg, int n, int K) {
    int t = blockIdx.x * blockDim.x + threadIdx.x;
    int lane = threadIdx.x & 63;
    int node = ((t >> 6) << 2) + (lane >> 4);   // 4 nodes per wave
    int sub = lane & 15;                        // half2 index
    if (node >= n) return;
    const __half2* xp = reinterpret_cast<const __half2*>(x16);
    float2 sv = __half22float2(xp[(size_t)node * 16 + sub]);
    float acc0 = sv.x, acc1 = sv.y;
    int i = off[node], e1 = off[node + 1];
    for (; i + 3 < e1; i += 4) {
        u64 eA = csr[i], eB = csr[i + 1], eC = csr[i + 2], eD = csr[i + 3];
        float2 hA = __half22float2(xp[(size_t)(eA >> 32) * 16 + sub]);
        float2 hB = __half22float2(xp[(size_t)(eB >> 32) * 16 + sub]);
        float2 hC = __half22float2(xp[(size_t)(eC >> 32) * 16 + sub]);
        float2 hD = __half22float2(xp[(size_t)(eD >> 32) * 16 + sub]);
        float wA = __uint_as_float((unsigned)eA);
        float wB = __uint_as_float((unsigned)eB);
        float wC = __uint_as_float((unsigned)eC);
        float wD = __uint_as_float((unsigned)eD);
        acc0 = fmaf(wA, hA.x, acc0); acc1 = fmaf(wA, hA.y, acc1);
        acc0 = fmaf(wB, hB.x, acc0); acc1 = fmaf(wB, hB.y, acc1);
        acc0 = fmaf(wC, hC.x, acc0); acc1 = fmaf(wC, hC.y, acc1);
        acc0 = fmaf(wD, hD.x, acc0); acc1 = fmaf(wD, hD.y, acc1);
    }
    for (; i < e1; ++i) {
        u64 eA = csr[i];
        float2 hA = __half22float2(xp[(size_t)(eA >> 32) * 16 + sub]);
        float wA = __uint_as_float((unsigned)eA);
        acc0 = fmaf(wA, hA.x, acc0); acc1 = fmaf(wA, hA.y, acc1);
    }
    int c0 = sub * 2;
    if (c0 < K) {   // K is even; pairs never straddle
        float d = dinv[node];
        float2 o; o.x = d * acc0; o.y = d * acc1;
        *reinterpret_cast<float2*>(agg + (size_t)node * K + c0) = o;
    }
}

// Tiled GEMM + bias + relu: out[n][64] = relu(in[n][K] @ W + b), fp32 out.
template <int K>
__global__ __launch_bounds__(256) void k_gemm_bias_relu(const float* __restrict__ x,
                                                        const float* __restrict__ W,
                                                        const float* __restrict__ bias,
                                                        float* __restrict__ out, int n) {
    __shared__ float xs[K * XS_STRIDE];
    __shared__ float ws[K * HIDC];
    int tid = threadIdx.x;
    int n0 = blockIdx.x * MTILE;

    for (int i = tid; i < K * HIDC; i += 256) ws[i] = W[i];
    for (int i = tid; i < MTILE * K; i += 256) {
        int r = i / K, k = i - r * K;
        float v = (n0 + r < n) ? x[(size_t)(n0 + r) * K + k] : 0.f;
        xs[k * XS_STRIDE + r] = v;
    }
    __syncthreads();

    int c0 = (tid & 15) * 4;
    int m0 = (tid >> 4) * 8;
    float acc[8][4];
#pragma unroll
    for (int j = 0; j < 8; ++j)
#pragma unroll
        for (int q = 0; q < 4; ++q) acc[j][q] = 0.f;

#pragma unroll 4
    for (int k = 0; k < K; ++k) {
        float4 a0 = *reinterpret_cast<const float4*>(&xs[k * XS_STRIDE + m0]);
        float4 a1 = *reinterpret_cast<const float4*>(&xs[k * XS_STRIDE + m0 + 4]);
        float4 b  = *reinterpret_cast<const float4*>(&ws[k * HIDC + c0]);
        float av[8] = {a0.x, a0.y, a0.z, a0.w, a1.x, a1.y, a1.z, a1.w};
        float bv[4] = {b.x, b.y, b.z, b.w};
#pragma unroll
        for (int j = 0; j < 8; ++j)
#pragma unroll
            for (int q = 0; q < 4; ++q)
                acc[j][q] = fmaf(av[j], bv[q], acc[j][q]);
    }

    float4 bb = *reinterpret_cast<const float4*>(bias + c0);
#pragma unroll
    for (int j = 0; j < 8; ++j) {
        int node = n0 + m0 + j;
        if (node < n) {
            float4 v;
            v.x = fmaxf(acc[j][0] + bb.x, 0.f);
            v.y = fmaxf(acc[j][1] + bb.y, 0.f);
            v.z = fmaxf(acc[j][2] + bb.z, 0.f);
            v.w = fmaxf(acc[j][3] + bb.w, 0.f);
            *reinterpret_cast<float4*>(out + (size_t)node * HIDC + c0) = v;
        }
    }
}

// Tiled GEMM: h'[n][64] = dinv[n] * (x[n][64] @ W), output fp16 (RNE).
template <int K>
__global__ __launch_bounds__(256) void k_gemm_tile(const float* __restrict__ x,
                                                   const float* __restrict__ W,
                                                   const float* __restrict__ dinv,
                                                   __half* __restrict__ h, int n) {
    __shared__ float xs[K * XS_STRIDE];
    __shared__ float ws[K * HIDC];
    int tid = threadIdx.x;
    int n0 = blockIdx.x * MTILE;

    for (int i = tid; i < K * HIDC; i += 256) ws[i] = W[i];

    constexpr int KQ = K / 4;
    for (int i = tid; i < MTILE * KQ; i += 256) {
        int r = i / KQ, kq = i - r * KQ;
        float4 v = make_float4(0.f, 0.f, 0.f, 0.f);
        if (n0 + r < n)
            v = *reinterpret_cast<const float4*>(x + (size_t)(n0 + r) * K + kq * 4);
        int k0 = kq * 4;
        xs[(k0 + 0) * XS_STRIDE + r] = v.x;
        xs[(k0 + 1) * XS_STRIDE + r] = v.y;
        xs[(k0 + 2) * XS_STRIDE + r] = v.z;
        xs[(k0 + 3) * XS_STRIDE + r] = v.w;
    }
    __syncthreads();

    int c0 = (tid & 15) * 4;
    int m0 = (tid >> 4) * 8;
    float acc[8][4];
#pragma unroll
    for (int j = 0; j < 8; ++j)
#pragma unroll
        for (int q = 0; q < 4; ++q) acc[j][q] = 0.f;

#pragma unroll 4
    for (int k = 0; k < K; ++k) {
        float4 a0 = *reinterpret_cast<const float4*>(&xs[k * XS_STRIDE + m0]);
        float4 a1 = *reinterpret_cast<const float4*>(&xs[k * XS_STRIDE + m0 + 4]);
        float4 b  = *reinterpret_cast<const float4*>(&ws[k * HIDC + c0]);
        float av[8] = {a0.x, a0.y, a0.z, a0.w, a1.x, a1.y, a1.z, a1.w};
        float bv[4] = {b.x, b.y, b.z, b.w};
#pragma unroll
        for (int j = 0; j < 8; ++j)
#pragma unroll
            for (int q = 0; q < 4; ++q)
                acc[j][q] = fmaf(av[j], bv[q], acc[j][q]);
    }

#pragma unroll
    for (int j = 0; j < 8; ++j) {
        int node = n0 + m0 + j;
        if (node < n) {
            float dv = dinv[node];
            union { struct { __half2 a, b; } h2; float2 f2; } u;
            u.h2.a = __floats2half2_rn(acc[j][0] * dv, acc[j][1] * dv);
            u.h2.b = __floats2half2_rn(acc[j][2] * dv, acc[j][3] * dv);
            *reinterpret_cast<float2*>(h + (size_t)node * HIDC + c0) = u.f2;
        }
    }
}

// Layer-2 gather: 2 nodes/wave, half2 loads, 8-wide edge unroll -> 16 fetches
// in flight. out = dinv[c]*(h'[c] + sum_e ew_e*h'[src_e]) + b, relu.
__global__ void k_gcn_gather(const __half* __restrict__ h, const int* __restrict__ off,
                             const u64* __restrict__ csr, const float* __restrict__ dinv,
                             const float* __restrict__ bias, float* __restrict__ out, int n) {
    int t = blockIdx.x * blockDim.x + threadIdx.x;
    int lane = threadIdx.x & 63;
    int node = ((t >> 6) << 1) + (lane >> 5);
    int sub = lane & 31;
    if (node >= n) return;
    const __half2* hp = reinterpret_cast<const __half2*>(h);
    float d = dinv[node];
    float2 sv = __half22float2(hp[(size_t)node * 32 + sub]);
    float acc0 = sv.x, acc1 = sv.y;
    int i = off[node], e1 = off[node + 1];
    for (; i + 7 < e1; i += 8) {
        u64 e0 = csr[i], e1_ = csr[i + 1], e2 = csr[i + 2], e3 = csr[i + 3];
        u64 e4 = csr[i + 4], e5 = csr[i + 5], e6 = csr[i + 6], e7 = csr[i + 7];
        float2 h0 = __half22float2(hp[(size_t)(e0 >> 32) * 32 + sub]);
        float2 h1 = __half22float2(hp[(size_t)(e1_ >> 32) * 32 + sub]);
        float2 h2 = __half22float2(hp[(size_t)(e2 >> 32) * 32 + sub]);
        float2 h3 = __half22float2(hp[(size_t)(e3 >> 32) * 32 + sub]);
        float2 h4 = __half22float2(hp[(size_t)(e4 >> 32) * 32 + sub]);
        float2 h5 = __half22float2(hp[(size_t)(e5 >> 32) * 32 + sub]);
        float2 h6 = __half22float2(hp[(size_t)(e6 >> 32) * 32 + sub]);
        float2 h7 = __half22float2(hp[(size_t)(e7 >> 32) * 32 + sub]);
        float w0 = __uint_as_float((unsigned)e0), w1 = __uint_as_float((unsigned)e1_);
        float w2 = __uint_as_float((unsigned)e2), w3 = __uint_as_float((unsigned)e3);
        float w4 = __uint_as_float((unsigned)e4), w5 = __uint_as_float((unsigned)e5);
        float w6 = __uint_as_float((unsigned)e6), w7 = __uint_as_float((unsigned)e7);
        acc0 = fmaf(w0, h0.x, acc0); acc1 = fmaf(w0, h0.y, acc1);
        acc0 = fmaf(w1, h1.x, acc0); acc1 = fmaf(w1, h1.y, acc1);
        acc0 = fmaf(w2, h2.x, acc0); acc1 = fmaf(w2, h2.y, acc1);
        acc0 = fmaf(w3, h3.x, acc0); acc1 = fmaf(w3, h3.y, acc1);
        acc0 = fmaf(w4, h4.x, acc0); acc1 = fmaf(w4, h4.y, acc1);
        acc0 = fmaf(w5, h5.x, acc0); acc1 = fmaf(w5, h5.y, acc1);
        acc0 = fmaf(w6, h6.x, acc0); acc1 = fmaf(w6, h6.y, acc1);
        acc0 = fmaf(w7, h7.x, acc0); acc1 = fmaf(w7, h7.y, acc1);
    }
    for (; i + 1 < e1; i += 2) {
        u64 eA = csr[i], eB = csr[i + 1];
        float2 hA = __half22float2(hp[(size_t)(eA >> 32) * 32 + sub]);
        float2 hB = __half22float2(hp[(size_t)(eB >> 32) * 32 + sub]);
        float wA = __uint_as_float((unsigned)eA);
        float wB = __uint_as_float((unsigned)eB);
        acc0 = fmaf(wA, hA.x, acc0); acc1 = fmaf(wA, hA.y, acc1);
        acc0 = fmaf(wB, hB.x, acc0); acc1 = fmaf(wB, hB.y, acc1);
    }
    if (i < e1) {
        u64 eA = csr[i];
        float2 hA = __half22float2(hp[(size_t)(eA >> 32) * 32 + sub]);
        float wA = __uint_as_float((unsigned)eA);
        acc0 = fmaf(wA, hA.x, acc0); acc1 = fmaf(wA, hA.y, acc1);
    }
    int c0 = sub * 2;
    float2 o;
    o.x = fmaxf(fmaf(d, acc0, bias[c0]), 0.f);
    o.y = fmaxf(fmaf(d, acc1, bias[c0 + 1]), 0.f);
    *reinterpret_cast<float2*>(out + (size_t)node * HIDC + c0) = o;
}

__global__ void k_zero(float* p, int n) {
    int i = blockIdx.x * blockDim.x + threadIdx.x;
    if (i < n) p[i] = 0.f;
}

// batch is sorted: segmented accumulate, flush (atomic) only on graph change.
__global__ void k_pool(const float* __restrict__ h, const int* __restrict__ batch,
                       float* __restrict__ pooled, float* __restrict__ cnt, int n) {
    int c = threadIdx.x & 63, sub = threadIdx.x >> 6;
    int n0 = blockIdx.x * 256;
    int nend = min(n0 + 256, n);
    float acc = 0.f, cacc = 0.f;
    int curb = -1;
    for (int i = n0 + sub; i < nend; i += 4) {
        int b = batch[i];
        if (b != curb) {
            if (curb >= 0) {
                atomicAdd(&pooled[curb * HIDC + c], acc);
                if (c == 0) atomicAdd(&cnt[curb], cacc);
            }
            acc = 0.f; cacc = 0.f;
            curb = b;
        }
        acc += h[(size_t)i * HIDC + c];
        cacc += 1.f;
    }
    if (curb >= 0) {
        atomicAdd(&pooled[curb * HIDC + c], acc);
        if (c == 0) atomicAdd(&cnt[curb], cacc);
    }
}

// One 64-thread block per graph: mean, fc1+relu, fc2.
__global__ void k_head(const float* __restrict__ pooled, const float* __restrict__ cnt,
                       const float* __restrict__ fw1, const float* __restrict__ fb1,
                       const float* __restrict__ fw2, const float* __restrict__ fb2,
                       float* __restrict__ out, int nclass) {
    int g = blockIdx.x;
    int j = threadIdx.x;
    __shared__ float p[HIDC], hid[HIDC];
    float c = fmaxf(cnt[g], 1.0f);
    p[j] = pooled[g * HIDC + j] / c;
    __syncthreads();
    float acc = fb1[j];
#pragma unroll 8
    for (int k = 0; k < HIDC; ++k) acc = fmaf(p[k], fw1[k * HIDC + j], acc);
    hid[j] = fmaxf(acc, 0.f);
    __syncthreads();
    if (j < nclass) {
        float o = fb2[j];
#pragma unroll 8
        for (int k = 0; k < HIDC; ++k) o = fmaf(hid[k], fw2[k * nclass + j], o);
        out[g * nclass + j] = o;
    }
}

extern "C" void kernel_launch(void* const* d_in, const int* in_sizes, int n_in,
                              void* d_out, int out_size, void* d_ws, size_t ws_size,
                              hipStream_t stream) {
    const float* x    = (const float*)d_in[0];
    const int* eidx   = (const int*)d_in[1];
    const float* ew   = (const float*)d_in[2];
    const int* batch  = (const int*)d_in[3];
    const float* W1   = (const float*)d_in[4];
    const float* b1   = (const float*)d_in[5];
    const float* W2   = (const float*)d_in[6];
    const float* b2   = (const float*)d_in[7];
    const float* fw1  = (const float*)d_in[8];
    const float* fb1  = (const float*)d_in[9];
    const float* fw2  = (const float*)d_in[10];
    const float* fb2  = (const float*)d_in[11];
    float* out = (float*)d_out;

    const int N = in_sizes[3];
    const int E = in_sizes[1] / 2;
    const int INCH = in_sizes[0] / N;          // 22
    const int NCLASS = in_sizes[11];
    const int G = out_size / NCLASS;
    const int NB = (N + SPAN - 1) >> BSHIFT;   // 196 for N=100000 (<=256 req.)

    const int* row = eidx;
    const int* col = eidx + E;

    // ---- workspace layout (8B-aligned arrays first) ----
    char* wp = (char*)d_ws;
    u64*   bedges = (u64*)wp;    wp += sizeof(u64) * E;
    u64*   csr    = (u64*)wp;    wp += sizeof(u64) * E;
    float* dinv   = (float*)wp;  wp += sizeof(float) * N;
    __half* x16   = (__half*)wp; wp += sizeof(__half) * (size_t)N * 32;
    float* agg    = (float*)wp;  wp += sizeof(float) * (size_t)N * INCH;
    __half* hbuf  = (__half*)wp; wp += sizeof(__half) * (size_t)N * HIDC;
    float* bufB   = (float*)wp;  wp += sizeof(float) * (size_t)N * HIDC;
    float* pooled = (float*)wp;  wp += sizeof(float) * (size_t)G * HIDC;
    float* cnt    = (float*)wp;  wp += sizeof(float) * G;
    int*   off    = (int*)wp;    wp += sizeof(int) * (N + 1);
    int*   bucket_cnt  = (int*)wp; wp += sizeof(int) * NBKT_MAX;
    int*   bucket_base = (int*)wp; wp += sizeof(int) * (NBKT_MAX + 1);
    int*   cursor_g    = (int*)wp; wp += sizeof(int) * NBKT_MAX;

    const int BLK = 256;
    dim3 blk(BLK);
    int gTile = (N + MTILE - 1) / MTILE;
    int gGather = (N + 7) / 8;     // 2 nodes/wave * 4 waves
    int gAggX   = (N + 15) / 16;   // 4 nodes/wave * 4 waves
    int gPrep   = ((size_t)N * 16 + BLK - 1) / BLK;

    // CSR build via bucket partition
    k_zero_int<<<1, blk, 0, stream>>>(bucket_cnt, NB);
    k_bin_count<<<(E + 8191) / 8192, blk, 0, stream>>>(col, bucket_cnt, E, NB);
    k_bucket_scan<<<1, blk, 0, stream>>>(bucket_cnt, bucket_base, cursor_g, NB, E);
    k_bin_scatter<<<(E + BCHUNK - 1) / BCHUNK, blk, 0, stream>>>(row, col, ew, cursor_g,
                                                                 bedges, E, NB);
    k_bucket_process<<<NB, blk, 0, stream>>>(bedges, bucket_base, csr, dinv, off, N, E, NB);

    // layer 1 (aggregate-then-transform): x16 = fp16(dinv*x) ; agg = dinv*(x16 + sum w x16[src]) ;
    // bufB = relu(agg @ W1 + b1)
    k_prep_x16<<<gPrep, blk, 0, stream>>>(x, dinv, x16, N, INCH);
    k_agg_x<<<gAggX, blk, 0, stream>>>(x16, off, csr, dinv, agg, N, INCH);
    k_gemm_bias_relu<22><<<gTile, blk, 0, stream>>>(agg, W1, b1, bufB, N);

    // layer 2 (transform-then-aggregate): hbuf = fp16(dinv*(bufB@W2)) ; gather+bias+relu -> bufB
    k_gemm_tile<64><<<gTile, blk, 0, stream>>>(bufB, W2, dinv, hbuf, N);
    k_gcn_gather<<<gGather, blk, 0, stream>>>(hbuf, off, csr, dinv, b2, bufB, N);

    // pool (count fused)
    int zeroN = G * HIDC + G;
    k_zero<<<(zeroN + BLK - 1) / BLK, blk, 0, stream>>>(pooled, zeroN);
    k_pool<<<(N + 255) / 256, blk, 0, stream>>>(bufB, batch, pooled, cnt, N);

    // head
    k_head<<<G, dim3(64), 0, stream>>>(pooled, cnt, fw1, fb1, fw2, fb2, out, NCLASS);
}

// Round 9
// 192.962 us; speedup vs baseline: 11.5318x; 1.0523x over previous
//
#include <hip/hip_runtime.h>
#include <hip/hip_bf16.h>
#include <hip/hip_fp16.h>

// GCN forward: 2x GCNConv(relu) -> global_mean_pool -> MLP head.
// Round 9: deeper gather MLP (32-64 rows in flight/wave); layer-1 GEMM pair
//          fused via LDS transpose (no bufB roundtrip); init kernels merged.

#define HIDC 64
#define MTILE 128
#define XS_STRIDE (MTILE + 4)
#define BSHIFT 9
#define SPAN 512          // nodes per bucket
#define NBKT_MAX 256      // requires N <= 131072
#define BCHUNK 2048       // edges per workgroup in k_bin_scatter

typedef unsigned long long u64;

// zero bucket_cnt (NB ints) + pooled/cnt (G*65 floats, contiguous)
__global__ void k_init(int* bucket_cnt, int nb, float* pooled, int npool) {
    int i = blockIdx.x * blockDim.x + threadIdx.x;
    if (i < nb) bucket_cnt[i] = 0;
    if (i < npool) pooled[i] = 0.f;
}

// per-workgroup LDS histogram of edge destinations by bucket
__global__ __launch_bounds__(256) void k_bin_count(const int* __restrict__ col,
                                                   int* bucket_cnt, int E, int NB) {
    __shared__ int hist[NBKT_MAX];
    int tid = threadIdx.x;
    for (int i = tid; i < NB; i += 256) hist[i] = 0;
    __syncthreads();
    int base = blockIdx.x * 8192;
    for (int j = 0; j < 32; ++j) {
        int e = base + j * 256 + tid;
        if (e < E) atomicAdd(&hist[col[e] >> BSHIFT], 1);
    }
    __syncthreads();
    for (int i = tid; i < NB; i += 256)
        if (hist[i]) atomicAdd(&bucket_cnt[i], hist[i]);
}

// exclusive scan of bucket counts (NB <= 256); emits base + cursor copy
__global__ void k_bucket_scan(const int* __restrict__ bucket_cnt, int* __restrict__ bucket_base,
                              int* __restrict__ cursor_g, int NB, int E) {
    __shared__ int s[256];
    int t = threadIdx.x;
    int v = (t < NB) ? bucket_cnt[t] : 0;
    s[t] = v;
    __syncthreads();
    for (int o = 1; o < 256; o <<= 1) {
        int x = (t >= o) ? s[t - o] : 0;
        __syncthreads();
        s[t] += x;
        __syncthreads();
    }
    if (t < NB) { int ex = s[t] - v; bucket_base[t] = ex; cursor_g[t] = ex; }
    if (t == 0) bucket_base[NB] = E;
}

// partition edges into destination buckets via LDS staging; flushes are
// contiguous runs per bucket (coalesced). packed = ew(32) | src(23) | colin(9).
__global__ __launch_bounds__(256) void k_bin_scatter(const int* __restrict__ row,
                                                     const int* __restrict__ col,
                                                     const float* __restrict__ ew,
                                                     int* cursor_g, u64* __restrict__ bedges,
                                                     int E, int NB) {
    __shared__ int hist[NBKT_MAX], binoff[NBKT_MAX], cursor[NBKT_MAX], gbase[NBKT_MAX];
    __shared__ int s[256];
    __shared__ u64 stage[BCHUNK];
    __shared__ unsigned char binid[BCHUNK];
    int tid = threadIdx.x;
    for (int i = tid; i < NB; i += 256) hist[i] = 0;
    __syncthreads();
    int base = blockIdx.x * BCHUNK;
    u64 pk[8]; int bb[8];
#pragma unroll
    for (int j = 0; j < 8; ++j) {
        int e = base + j * 256 + tid;
        if (e < E) {
            int c = col[e];
            bb[j] = c >> BSHIFT;
            pk[j] = ((u64)__float_as_uint(ew[e]) << 32) |
                    ((u64)(unsigned)row[e] << BSHIFT) | (unsigned)(c & (SPAN - 1));
            atomicAdd(&hist[bb[j]], 1);
        } else bb[j] = -1;
    }
    __syncthreads();
    {   // exclusive scan of hist -> binoff
        int v = (tid < NB) ? hist[tid] : 0;
        s[tid] = v;
        __syncthreads();
        for (int o = 1; o < 256; o <<= 1) {
            int x = (tid >= o) ? s[tid - o] : 0;
            __syncthreads();
            s[tid] += x;
            __syncthreads();
        }
        if (tid < NB) { binoff[tid] = s[tid] - v; cursor[tid] = s[tid] - v; }
    }
    __syncthreads();
#pragma unroll
    for (int j = 0; j < 8; ++j)
        if (bb[j] >= 0) {
            int pos = atomicAdd(&cursor[bb[j]], 1);
            stage[pos] = pk[j];
            binid[pos] = (unsigned char)bb[j];
        }
    __syncthreads();
    if (tid < NB && hist[tid] > 0) gbase[tid] = atomicAdd(&cursor_g[tid], hist[tid]);
    __syncthreads();
    int total = min(BCHUNK, E - base);
    for (int i = tid; i < total; i += 256) {
        int b = binid[i];
        bedges[(size_t)gbase[b] + (i - binoff[b])] = stage[i];
    }
}

// one workgroup per bucket: LDS degree/count accumulate, LDS scan -> CSR offsets,
// in-bucket scatter (L2-resident region), emit dinv + off coalesced.
__global__ __launch_bounds__(256) void k_bucket_process(const u64* __restrict__ bedges,
                                                        const int* __restrict__ bucket_base,
                                                        u64* __restrict__ csr,
                                                        float* __restrict__ dinv,
                                                        int* __restrict__ off,
                                                        int N, int E, int NB) {
    __shared__ float deg[SPAN];
    __shared__ int cL[SPAN];
    __shared__ int offL[SPAN];
    __shared__ int s[256];
    int b = blockIdx.x, tid = threadIdx.x;
    int ebase = bucket_base[b], ecnt = bucket_base[b + 1] - ebase;
    int nd0 = b << BSHIFT;
    int ndn = min(SPAN, N - nd0);
    for (int i = tid; i < SPAN; i += 256) { deg[i] = 1.0f; cL[i] = 0; }
    __syncthreads();
    for (int e = tid; e < ecnt; e += 256) {
        u64 p = bedges[ebase + e];
        int colin = (int)(p & (SPAN - 1));
        atomicAdd(&deg[colin], __uint_as_float((unsigned)(p >> 32)));
        atomicAdd(&cL[colin], 1);
    }
    __syncthreads();
    // exclusive scan of cL[0..SPAN) via pairs (SPAN = 2*256)
    int p0 = cL[2 * tid], p1 = cL[2 * tid + 1];
    s[tid] = p0 + p1;
    __syncthreads();
    for (int o = 1; o < 256; o <<= 1) {
        int x = (tid >= o) ? s[tid - o] : 0;
        __syncthreads();
        s[tid] += x;
        __syncthreads();
    }
    int ex = s[tid] - (p0 + p1);
    offL[2 * tid] = ex;
    offL[2 * tid + 1] = ex + p0;
    __syncthreads();
    for (int i = tid; i < ndn; i += 256) {
        dinv[nd0 + i] = rsqrtf(deg[i]);
        off[nd0 + i] = ebase + offL[i];
    }
    for (int i = tid; i < SPAN; i += 256) cL[i] = offL[i];   // cursors
    if (b == NB - 1 && tid == 0) off[N] = E;
    __syncthreads();
    for (int e = tid; e < ecnt; e += 256) {
        u64 p = bedges[ebase + e];
        int colin = (int)(p & (SPAN - 1));
        int src = (int)((p >> BSHIFT) & 0x7FFFFF);   // 23 bits
        int slot = atomicAdd(&cL[colin], 1);
        csr[(size_t)ebase + slot] = ((u64)(unsigned)src << 32) | (unsigned)(p >> 32);
    }
}

// x16[n][32] = fp16(dinv[n] * x[n][0..21]), channels 22..31 zero (64B rows).
__global__ void k_prep_x16(const float* __restrict__ x, const float* __restrict__ dinv,
                           __half* __restrict__ x16, int n, int K) {
    int t = blockIdx.x * blockDim.x + threadIdx.x;
    int node = t >> 4, p = t & 15;     // 16 half2 per row
    if (node >= n) return;
    int c0 = p * 2;
    float d = dinv[node];
    float a = (c0 < K)     ? d * x[(size_t)node * K + c0]     : 0.f;
    float b = (c0 + 1 < K) ? d * x[(size_t)node * K + c0 + 1] : 0.f;
    reinterpret_cast<__half2*>(x16)[(size_t)node * 16 + p] = __floats2half2_rn(a, b);
}

// Layer-1 aggregation over raw x: 8 nodes/wave (8 lanes each, uint2 = 4ch/lane),
// 8-wide edge unroll -> up to 64 row fetches in flight per wave.
__global__ void k_agg_x(const __half* __restrict__ x16, const int* __restrict__ off,
                        const u64* __restrict__ csr, const float* __restrict__ dinv,
                        float* __restrict__ agg, int n, int K) {
    int t = blockIdx.x * blockDim.x + threadIdx.x;
    int lane = threadIdx.x & 63;
    int node = ((t >> 6) << 3) + (lane >> 3);   // 8 nodes per wave
    int sub = lane & 7;                         // uint2 index (4 channels)
    if (node >= n) return;
    const uint2* xp = reinterpret_cast<const uint2*>(x16);   // 8 uint2 per row
    uint2 sv = xp[(size_t)node * 8 + sub];
    float acc0, acc1, acc2, acc3;
    {
        float2 a = __half22float2(*(const __half2*)&sv.x);
        float2 b = __half22float2(*(const __half2*)&sv.y);
        acc0 = a.x; acc1 = a.y; acc2 = b.x; acc3 = b.y;
    }
    int i = off[node], e1 = off[node + 1];
    for (; i + 7 < e1; i += 8) {
        u64 e[8]; uint2 r[8];
#pragma unroll
        for (int j = 0; j < 8; ++j) e[j] = csr[i + j];
#pragma unroll
        for (int j = 0; j < 8; ++j) r[j] = xp[(size_t)(e[j] >> 32) * 8 + sub];
#pragma unroll
        for (int j = 0; j < 8; ++j) {
            float w = __uint_as_float((unsigned)e[j]);
            float2 a = __half22float2(*(const __half2*)&r[j].x);
            float2 b = __half22float2(*(const __half2*)&r[j].y);
            acc0 = fmaf(w, a.x, acc0); acc1 = fmaf(w, a.y, acc1);
            acc2 = fmaf(w, b.x, acc2); acc3 = fmaf(w, b.y, acc3);
        }
    }
    for (; i < e1; ++i) {
        u64 e0 = csr[i];
        uint2 r = xp[(size_t)(e0 >> 32) * 8 + sub];
        float w = __uint_as_float((unsigned)e0);
        float2 a = __half22float2(*(const __half2*)&r.x);
        float2 b = __half22float2(*(const __half2*)&r.y);
        acc0 = fmaf(w, a.x, acc0); acc1 = fmaf(w, a.y, acc1);
        acc2 = fmaf(w, b.x, acc2); acc3 = fmaf(w, b.y, acc3);
    }
    int c0 = sub * 4;
    float d = dinv[node];
    float* ap = agg + (size_t)node * K + c0;
    if (c0 + 3 < K) {
        float2 o0; o0.x = d * acc0; o0.y = d * acc1;
        float2 o1; o1.x = d * acc2; o1.y = d * acc3;
        *reinterpret_cast<float2*>(ap) = o0;
        *reinterpret_cast<float2*>(ap + 2) = o1;
    } else if (c0 < K) {   // K=22: c0==20 -> last 2 channels
        float2 o; o.x = d * acc0; o.y = d * acc1;
        *reinterpret_cast<float2*>(ap) = o;
    }
}

// Fused layer-1 transform: hbuf = fp16(dinv * (relu(agg@W1 + b1) @ W2)).
// GEMM1 -> relu -> LDS transpose -> GEMM2, all in one block per 128-node tile.
template <int K1>
__global__ __launch_bounds__(256) void k_layer1_fused(const float* __restrict__ agg,
                                                      const float* __restrict__ W1,
                                                      const float* __restrict__ b1,
                                                      const float* __restrict__ W2,
                                                      const float* __restrict__ dinv,
                                                      __half* __restrict__ h, int n) {
    __shared__ float smem[HIDC * XS_STRIDE];   // phase1: agg^T tile; phase2: relu^T tile
    __shared__ float ws[HIDC * HIDC];          // phase1: W1; phase2: W2
    int tid = threadIdx.x;
    int n0 = blockIdx.x * MTILE;

    for (int i = tid; i < K1 * HIDC; i += 256) ws[i] = W1[i];
    for (int i = tid; i < MTILE * K1; i += 256) {
        int r = i / K1, k = i - r * K1;
        smem[k * XS_STRIDE + r] = (n0 + r < n) ? agg[(size_t)(n0 + r) * K1 + k] : 0.f;
    }
    __syncthreads();

    int c0 = (tid & 15) * 4;
    int m0 = (tid >> 4) * 8;
    float acc[8][4];
#pragma unroll
    for (int j = 0; j < 8; ++j)
#pragma unroll
        for (int q = 0; q < 4; ++q) acc[j][q] = 0.f;

#pragma unroll 2
    for (int k = 0; k < K1; ++k) {
        float4 a0 = *reinterpret_cast<const float4*>(&smem[k * XS_STRIDE + m0]);
        float4 a1 = *reinterpret_cast<const float4*>(&smem[k * XS_STRIDE + m0 + 4]);
        float4 b  = *reinterpret_cast<const float4*>(&ws[k * HIDC + c0]);
        float av[8] = {a0.x, a0.y, a0.z, a0.w, a1.x, a1.y, a1.z, a1.w};
        float bv[4] = {b.x, b.y, b.z, b.w};
#pragma unroll
        for (int j = 0; j < 8; ++j)
#pragma unroll
            for (int q = 0; q < 4; ++q)
                acc[j][q] = fmaf(av[j], bv[q], acc[j][q]);
    }

    float4 bb = *reinterpret_cast<const float4*>(b1 + c0);
    float bv4[4] = {bb.x, bb.y, bb.z, bb.w};
#pragma unroll
    for (int j = 0; j < 8; ++j)
#pragma unroll
        for (int q = 0; q < 4; ++q)
            acc[j][q] = fmaxf(acc[j][q] + bv4[q], 0.f);

    __syncthreads();   // phase-1 reads done; smem/ws reusable

    // write relu tile transposed: smem[ch][row]
#pragma unroll
    for (int j = 0; j < 8; ++j)
#pragma unroll
        for (int q = 0; q < 4; ++q)
            smem[(c0 + q) * XS_STRIDE + (m0 + j)] = (n0 + m0 + j < n) ? acc[j][q] : 0.f;
    for (int i = tid; i < HIDC * HIDC; i += 256) ws[i] = W2[i];
    __syncthreads();

#pragma unroll
    for (int j = 0; j < 8; ++j)
#pragma unroll
        for (int q = 0; q < 4; ++q) acc[j][q] = 0.f;

#pragma unroll 2
    for (int k = 0; k < HIDC; ++k) {
        float4 a0 = *reinterpret_cast<const float4*>(&smem[k * XS_STRIDE + m0]);
        float4 a1 = *reinterpret_cast<const float4*>(&smem[k * XS_STRIDE + m0 + 4]);
        float4 b  = *reinterpret_cast<const float4*>(&ws[k * HIDC + c0]);
        float av[8] = {a0.x, a0.y, a0.z, a0.w, a1.x, a1.y, a1.z, a1.w};
        float bv[4] = {b.x, b.y, b.z, b.w};
#pragma unroll
        for (int j = 0; j < 8; ++j)
#pragma unroll
            for (int q = 0; q < 4; ++q)
                acc[j][q] = fmaf(av[j], bv[q], acc[j][q]);
    }

#pragma unroll
    for (int j = 0; j < 8; ++j) {
        int node = n0 + m0 + j;
        if (node < n) {
            float dv = dinv[node];
            union { struct { __half2 a, b; } h2; float2 f2; } u;
            u.h2.a = __floats2half2_rn(acc[j][0] * dv, acc[j][1] * dv);
            u.h2.b = __floats2half2_rn(acc[j][2] * dv, acc[j][3] * dv);
            *reinterpret_cast<float2*>(h + (size_t)node * HIDC + c0) = u.f2;
        }
    }
}

// Layer-2 gather: 4 nodes/wave (16 lanes x uint2 = 4ch), 8-wide edge unroll
// -> 32 row fetches in flight. out = relu(dinv*(h'self + sum w*h'src) + b).
__global__ void k_gcn_gather(const __half* __restrict__ h, const int* __restrict__ off,
                             const u64* __restrict__ csr, const float* __restrict__ dinv,
                             const float* __restrict__ bias, float* __restrict__ out, int n) {
    int t = blockIdx.x * blockDim.x + threadIdx.x;
    int lane = threadIdx.x & 63;
    int node = ((t >> 6) << 2) + (lane >> 4);   // 4 nodes per wave
    int sub = lane & 15;                        // uint2 index (4 channels)
    if (node >= n) return;
    const uint2* hp = reinterpret_cast<const uint2*>(h);   // 16 uint2 per row
    float d = dinv[node];
    uint2 sv = hp[(size_t)node * 16 + sub];
    float acc0, acc1, acc2, acc3;
    {
        float2 a = __half22float2(*(const __half2*)&sv.x);
        float2 b = __half22float2(*(const __half2*)&sv.y);
        acc0 = a.x; acc1 = a.y; acc2 = b.x; acc3 = b.y;
    }
    int i = off[node], e1 = off[node + 1];
    for (; i + 7 < e1; i += 8) {
        u64 e[8]; uint2 r[8];
#pragma unroll
        for (int j = 0; j < 8; ++j) e[j] = csr[i + j];
#pragma unroll
        for (int j = 0; j < 8; ++j) r[j] = hp[(size_t)(e[j] >> 32) * 16 + sub];
#pragma unroll
        for (int j = 0; j < 8; ++j) {
            float w = __uint_as_float((unsigned)e[j]);
            float2 a = __half22float2(*(const __half2*)&r[j].x);
            float2 b = __half22float2(*(const __half2*)&r[j].y);
            acc0 = fmaf(w, a.x, acc0); acc1 = fmaf(w, a.y, acc1);
            acc2 = fmaf(w, b.x, acc2); acc3 = fmaf(w, b.y, acc3);
        }
    }
    for (; i < e1; ++i) {
        u64 e0 = csr[i];
        uint2 r = hp[(size_t)(e0 >> 32) * 16 + sub];
        float w = __uint_as_float((unsigned)e0);
        float2 a = __half22float2(*(const __half2*)&r.x);
        float2 b = __half22float2(*(const __half2*)&r.y);
        acc0 = fmaf(w, a.x, acc0); acc1 = fmaf(w, a.y, acc1);
        acc2 = fmaf(w, b.x, acc2); acc3 = fmaf(w, b.y, acc3);
    }
    int c0 = sub * 4;
    float4 bb = *reinterpret_cast<const float4*>(bias + c0);
    float4 o;
    o.x = fmaxf(fmaf(d, acc0, bb.x), 0.f);
    o.y = fmaxf(fmaf(d, acc1, bb.y), 0.f);
    o.z = fmaxf(fmaf(d, acc2, bb.z), 0.f);
    o.w = fmaxf(fmaf(d, acc3, bb.w), 0.f);
    *reinterpret_cast<float4*>(out + (size_t)node * HIDC + c0) = o;
}

// batch is sorted: segmented accumulate, flush (atomic) only on graph change.
__global__ void k_pool(const float* __restrict__ h, const int* __restrict__ batch,
                       float* __restrict__ pooled, float* __restrict__ cnt, int n) {
    int c = threadIdx.x & 63, sub = threadIdx.x >> 6;
    int n0 = blockIdx.x * 256;
    int nend = min(n0 + 256, n);
    float acc = 0.f, cacc = 0.f;
    int curb = -1;
    for (int i = n0 + sub; i < nend; i += 4) {
        int b = batch[i];
        if (b != curb) {
            if (curb >= 0) {
                atomicAdd(&pooled[curb * HIDC + c], acc);
                if (c == 0) atomicAdd(&cnt[curb], cacc);
            }
            acc = 0.f; cacc = 0.f;
            curb = b;
        }
        acc += h[(size_t)i * HIDC + c];
        cacc += 1.f;
    }
    if (curb >= 0) {
        atomicAdd(&pooled[curb * HIDC + c], acc);
        if (c == 0) atomicAdd(&cnt[curb], cacc);
    }
}

// One 64-thread block per graph: mean, fc1+relu, fc2.
__global__ void k_head(const float* __restrict__ pooled, const float* __restrict__ cnt,
                       const float* __restrict__ fw1, const float* __restrict__ fb1,
                       const float* __restrict__ fw2, const float* __restrict__ fb2,
                       float* __restrict__ out, int nclass) {
    int g = blockIdx.x;
    int j = threadIdx.x;
    __shared__ float p[HIDC], hid[HIDC];
    float c = fmaxf(cnt[g], 1.0f);
    p[j] = pooled[g * HIDC + j] / c;
    __syncthreads();
    float acc = fb1[j];
#pragma unroll 8
    for (int k = 0; k < HIDC; ++k) acc = fmaf(p[k], fw1[k * HIDC + j], acc);
    hid[j] = fmaxf(acc, 0.f);
    __syncthreads();
    if (j < nclass) {
        float o = fb2[j];
#pragma unroll 8
        for (int k = 0; k < HIDC; ++k) o = fmaf(hid[k], fw2[k * nclass + j], o);
        out[g * nclass + j] = o;
    }
}

extern "C" void kernel_launch(void* const* d_in, const int* in_sizes, int n_in,
                              void* d_out, int out_size, void* d_ws, size_t ws_size,
                              hipStream_t stream) {
    const float* x    = (const float*)d_in[0];
    const int* eidx   = (const int*)d_in[1];
    const float* ew   = (const float*)d_in[2];
    const int* batch  = (const int*)d_in[3];
    const float* W1   = (const float*)d_in[4];
    const float* b1   = (const float*)d_in[5];
    const float* W2   = (const float*)d_in[6];
    const float* b2   = (const float*)d_in[7];
    const float* fw1  = (const float*)d_in[8];
    const float* fb1  = (const float*)d_in[9];
    const float* fw2  = (const float*)d_in[10];
    const float* fb2  = (const float*)d_in[11];
    float* out = (float*)d_out;

    const int N = in_sizes[3];
    const int E = in_sizes[1] / 2;
    const int INCH = in_sizes[0] / N;          // 22
    const int NCLASS = in_sizes[11];
    const int G = out_size / NCLASS;
    const int NB = (N + SPAN - 1) >> BSHIFT;   // 196 for N=100000 (<=256 req.)

    const int* row = eidx;
    const int* col = eidx + E;

    // ---- workspace layout (8B-aligned arrays first) ----
    char* wp = (char*)d_ws;
    u64*   bedges = (u64*)wp;    wp += sizeof(u64) * E;
    u64*   csr    = (u64*)wp;    wp += sizeof(u64) * E;
    float* dinv   = (float*)wp;  wp += sizeof(float) * N;
    __half* x16   = (__half*)wp; wp += sizeof(__half) * (size_t)N * 32;
    float* agg    = (float*)wp;  wp += sizeof(float) * (size_t)N * INCH;
    __half* hbuf  = (__half*)wp; wp += sizeof(__half) * (size_t)N * HIDC;
    float* bufB   = (float*)wp;  wp += sizeof(float) * (size_t)N * HIDC;
    float* pooled = (float*)wp;  wp += sizeof(float) * (size_t)G * HIDC;
    float* cnt    = (float*)wp;  wp += sizeof(float) * G;
    int*   off    = (int*)wp;    wp += sizeof(int) * (N + 1);
    int*   bucket_cnt  = (int*)wp; wp += sizeof(int) * NBKT_MAX;
    int*   bucket_base = (int*)wp; wp += sizeof(int) * (NBKT_MAX + 1);
    int*   cursor_g    = (int*)wp; wp += sizeof(int) * NBKT_MAX;

    const int BLK = 256;
    dim3 blk(BLK);
    int gTile   = (N + MTILE - 1) / MTILE;
    int gGather = (N + 15) / 16;   // 4 nodes/wave * 4 waves
    int gAggX   = (N + 31) / 32;   // 8 nodes/wave * 4 waves
    int gPrep   = ((size_t)N * 16 + BLK - 1) / BLK;
    int nInit   = max(NB, G * HIDC + G);

    // init (bucket counts + pooled/cnt zeros)
    k_init<<<(nInit + BLK - 1) / BLK, blk, 0, stream>>>(bucket_cnt, NB, pooled, G * HIDC + G);

    // CSR build via bucket partition
    k_bin_count<<<(E + 8191) / 8192, blk, 0, stream>>>(col, bucket_cnt, E, NB);
    k_bucket_scan<<<1, blk, 0, stream>>>(bucket_cnt, bucket_base, cursor_g, NB, E);
    k_bin_scatter<<<(E + BCHUNK - 1) / BCHUNK, blk, 0, stream>>>(row, col, ew, cursor_g,
                                                                 bedges, E, NB);
    k_bucket_process<<<NB, blk, 0, stream>>>(bedges, bucket_base, csr, dinv, off, N, E, NB);

    // layer 1: x16 = fp16(dinv*x); agg = dinv*(x16self + sum w*x16src);
    //          hbuf = fp16(dinv * (relu(agg@W1+b1) @ W2))      (fused)
    k_prep_x16<<<gPrep, blk, 0, stream>>>(x, dinv, x16, N, INCH);
    k_agg_x<<<gAggX, blk, 0, stream>>>(x16, off, csr, dinv, agg, N, INCH);
    k_layer1_fused<22><<<gTile, blk, 0, stream>>>(agg, W1, b1, W2, dinv, hbuf, N);

    // layer 2 gather: bufB = relu(dinv*(hbuf_self + sum w*hbuf_src) + b2)
    k_gcn_gather<<<gGather, blk, 0, stream>>>(hbuf, off, csr, dinv, b2, bufB, N);

    // pool + head
    k_pool<<<(N + 255) / 256, blk, 0, stream>>>(bufB, batch, pooled, cnt, N);
    k_head<<<G, dim3(64), 0, stream>>>(pooled, cnt, fw1, fb1, fw2, fb2, out, NCLASS);
}